// Round 1
// baseline (1688.411 us; speedup 1.0000x reference)
//
#include <hip/hip_runtime.h>
#include <stdint.h>

typedef unsigned short u16;
typedef __attribute__((ext_vector_type(8))) short bf16x8;
typedef __attribute__((ext_vector_type(4))) float f32x4;

#define HD 256
#define AST 72        // A_lds row stride in u16 (144 B; rotates banks row-to-row)
#define CORR_CAP 8192 // backtracking-pair capacity (expected ~16 for this graph)

static __device__ __forceinline__ float b2f(u16 x){
  union{float f; unsigned u;} v; v.u = ((unsigned)x)<<16; return v.f;
}
static __device__ __forceinline__ u16 f2b(float f){
  union{float f; unsigned u;} v; v.f = f;
  unsigned r = v.u + 0x7fffu + ((v.u>>16)&1u);
  return (u16)(r>>16);
}
static __device__ __forceinline__ void acc4(float* a, uint2 v){
  a[0] += b2f((u16)v.x); a[1] += b2f((u16)(v.x>>16));
  a[2] += b2f((u16)v.y); a[3] += b2f((u16)(v.y>>16));
}

// ---------------- zero int buffer ----------------
__global__ void k_zero_int(int* __restrict__ p, int n){
  int i = blockIdx.x*256 + threadIdx.x;
  if (i < n) p[i] = 0;
}

// ---------------- histogram ----------------
__global__ void k_hist(const int* __restrict__ key, int* __restrict__ deg, int n){
  int i = blockIdx.x*256 + threadIdx.x;
  if (i < n) atomicAdd(&deg[key[i]], 1);
}

// ---------------- single-block exclusive scan ----------------
__global__ __launch_bounds__(1024) void k_scan(const int* __restrict__ deg, int* __restrict__ start,
                                               int* __restrict__ cursor, int n){
  __shared__ int sm[1024];
  const int t = threadIdx.x;
  const int chunk = (n + 1023) >> 10;
  const int lo = t*chunk, hi = min(lo+chunk, n);
  int s = 0;
  for (int i=lo;i<hi;i++) s += deg[i];
  sm[t] = s;
  __syncthreads();
  for (int ofs=1; ofs<1024; ofs<<=1){
    int v = (t>=ofs) ? sm[t-ofs] : 0;
    __syncthreads();
    sm[t] += v;
    __syncthreads();
  }
  int base = sm[t] - s;
  for (int i=lo;i<hi;i++){
    start[i] = base; cursor[i] = base;
    base += deg[i];
  }
  if (t == 1023) start[n] = sm[1023];
}

// ---------------- fill buckets ----------------
__global__ void k_fill(const int* __restrict__ key, const int* __restrict__ val,
                       int* __restrict__ cursor, int* __restrict__ bucket, int n){
  int i = blockIdx.x*256 + threadIdx.x;
  if (i >= n) return;
  int pos = atomicAdd(&cursor[key[i]], 1);
  bucket[pos] = val ? val[i] : i;
}

// ---------------- alpha16[v] = bf16( sum_{j} tree_m[bucket[j]] ) ----------------
__global__ void k_alpha_gather(const float* __restrict__ tree_m, const int* __restrict__ start,
                               const int* __restrict__ bucket, u16* __restrict__ alpha16, int N){
  int v = (int)(((long long)blockIdx.x*blockDim.x + threadIdx.x)>>6);
  int l = threadIdx.x & 63;
  if (v >= N) return;
  int s = start[v], e2 = start[v+1];
  float a0=0.f,a1=0.f,a2=0.f,a3=0.f;
  for (int j=s;j<e2;j++){
    float4 tv = *(const float4*)(tree_m + (long long)bucket[j]*HD + l*4);
    a0 += tv.x; a1 += tv.y; a2 += tv.z; a3 += tv.w;
  }
  ushort4 o; o.x=f2b(a0); o.y=f2b(a1); o.z=f2b(a2); o.w=f2b(a3);
  *(ushort4*)(alpha16 + (long long)v*HD + l*4) = o;
}

// ---------------- nodeacc[v] = bf16( alpha[v] + sum_{e: dst[e]=v} msg[e] ) ----------------
// Wave per node; dst-CSR bucket walk with unroll-4 msg-row reads (512 B coalesced each).
__global__ void k_nodesum(const u16* __restrict__ msg, const u16* __restrict__ alpha16,
                          const int* __restrict__ start_d, const int* __restrict__ bucket_d,
                          u16* __restrict__ nodeacc, int N){
  int v = (int)(((long long)blockIdx.x*blockDim.x + threadIdx.x)>>6);
  int l = threadIdx.x & 63;
  if (v >= N) return;
  int s = start_d[v], e2 = start_d[v+1];
  float a[4];
  { uint2 av = *(const uint2*)(alpha16 + (long long)v*HD + l*4);
    a[0]=b2f((u16)av.x); a[1]=b2f((u16)(av.x>>16));
    a[2]=b2f((u16)av.y); a[3]=b2f((u16)(av.y>>16)); }
  const u16* ml = msg + l*4;
  int j = s;
  for (; j+4 <= e2; j+=4){
    int q0=bucket_d[j], q1=bucket_d[j+1], q2=bucket_d[j+2], q3=bucket_d[j+3];
    uint2 v0 = *(const uint2*)(ml + (long long)q0*HD);
    uint2 v1 = *(const uint2*)(ml + (long long)q1*HD);
    uint2 v2 = *(const uint2*)(ml + (long long)q2*HD);
    uint2 v3 = *(const uint2*)(ml + (long long)q3*HD);
    acc4(a, v0); acc4(a, v1); acc4(a, v2); acc4(a, v3);
  }
  for (; j < e2; j++){
    uint2 v0 = *(const uint2*)(ml + (long long)bucket_d[j]*HD);
    acc4(a, v0);
  }
  ushort4 o; o.x=f2b(a[0]); o.y=f2b(a[1]); o.z=f2b(a[2]); o.w=f2b(a[3]);
  *(ushort4*)(nodeacc + (long long)v*HD + l*4) = o;
}

// ---------------- backtracking-pair CSR build (graph-constant, built once) ----------------
// corr segment of edge e lists edges e' with dst[e']==src[e] && src[e']==dst[e]
__global__ void k_corr_count(const int* __restrict__ esrc, const int* __restrict__ edst,
                             const int* __restrict__ start_d, const int* __restrict__ bucket_d,
                             int* __restrict__ deg_c, int E){
  int e = blockIdx.x*256 + threadIdx.x;
  if (e >= E) return;
  int u = esrc[e], v = edst[e];
  int s = start_d[u], t = start_d[u+1];
  int c = 0;
  for (int j=s;j<t;j++) if (esrc[bucket_d[j]] == v) c++;
  deg_c[e] = c;
}

__global__ void k_corr_fill(const int* __restrict__ esrc, const int* __restrict__ edst,
                            const int* __restrict__ start_d, const int* __restrict__ bucket_d,
                            const int* __restrict__ corr_start, int* __restrict__ corr_edge, int E){
  int e = blockIdx.x*256 + threadIdx.x;
  if (e >= E) return;
  int u = esrc[e], v = edst[e];
  int s = start_d[u], t = start_d[u+1];
  int pos = corr_start[e];
  for (int j=s;j<t;j++){
    int ep = bucket_d[j];
    if (esrc[ep] == v){ if (pos < CORR_CAP) corr_edge[pos] = ep; pos++; }
  }
}

// snapshot corr msg rows before in-place msg overwrite
__global__ void k_snapshot(const u16* __restrict__ msg, const int* __restrict__ corr_edge,
                           const int* __restrict__ totalp, u16* __restrict__ corrbuf){
  int g = blockIdx.x*256 + threadIdx.x;
  int p = g>>6, l = g&63;
  int total = *totalp; if (total > CORR_CAP) total = CORR_CAP;
  if (p >= total) return;
  int e = corr_edge[p];
  *(uint2*)(corrbuf + (long long)p*HD + l*4) =
      *(const uint2*)(msg + (long long)e*HD + l*4);
}

// ---------------- frag-major B prep ----------------
__global__ void k_prep_B(const float* __restrict__ Wi, const float* __restrict__ Wh,
                         const float* __restrict__ Wo,
                         u16* __restrict__ BTf_bp, u16* __restrict__ BTf_fo){
  int g = blockIdx.x*256 + threadIdx.x;   // 81920 total
  if (g >= 81920) return;
  int i = g & 7;
  int l = (g>>3) & 63;
  int t = g >> 9;                // 0..159
  int nj = t & 15, ks = t >> 4;  // ks 0..9
  int n = nj*16 + (l & 15);
  int k = ks*32 + (l>>4)*8 + i;
  float bp = 0.f, fo = 0.f;
  if (k < 40) bp = Wi[k*HD + n];
  else if (k >= 64) bp = Wh[(k-64)*HD + n];
  if (k < 35) fo = Wo[k*HD + n];
  else if (k >= 64) fo = Wo[(k-29)*HD + n];
  BTf_bp[g] = f2b(bp);
  BTf_fo[g] = f2b(fo);
}

// ---------------- fused MPNN GEMM, wave-per-16-rows ----------------
// mode 0: A=[x_src|xe|0], ksteps 2
// mode 1: A=[x_src|xe| nodeacc[src]-corr ], ksteps 10 (out16, in-place msg)
// mode 2: A=[x_node|0| nodeacc[row] ], ksteps 10 (out32, +bias)
// cols [64,320) A-frags loaded DIRECTLY from nodeacc (contiguous row) — no LDS staging.
__global__ __launch_bounds__(256, 3) void k_mpnn(
    const float* __restrict__ xn, const float* __restrict__ xe,
    const u16* __restrict__ nacc, const u16* __restrict__ corrbuf,
    const int* __restrict__ corr_start, const int* __restrict__ esrc,
    const u16* __restrict__ BTf, const float* __restrict__ bias,
    u16* __restrict__ out16, float* __restrict__ out32, int M, int mode)
{
  __shared__ u16 A_lds[4][16][AST];   // 9,216 B
  const int tid = threadIdx.x;
  const int wave = tid>>6, l = tid&63;
  const int lr = l&15, lq = l>>4;
  const int m0 = blockIdx.x*64 + wave*16;
  u16* Aw = &A_lds[wave][0][0];

  // per-lane row metadata (all lq groups redundantly compute; __shfl(x, r) reads lane r)
  const int rowl = m0 + lr;
  const bool rvl = rowl < M;
  int srcl = 0, sl = 0, el = 0;
  if (rvl){
    srcl = (mode==2) ? rowl : esrc[rowl];
    if (mode == 1){ sl = corr_start[rowl]; el = corr_start[rowl+1]; }
  }

  // ---- direct A-frags for cols [64,320): issue early to hide latency
  bf16x8 af[10];
  if (mode != 0){
    const u16* nrow = nacc + (long long)srcl*HD + lq*8;
    #pragma unroll
    for (int ks=2; ks<10; ks++)
      af[ks] = *(const bf16x8*)(nrow + (ks-2)*32);
  }

  // ---- stage features cols [0,64): coalesced per-row loads via LDS transpose
  for (int r=0; r<16; r++){
    int sv = __shfl(srcl, r);
    int rw = m0 + r;
    float v = 0.f;
    if (rw < M){
      if (l < 35) v = xn[(long long)sv*35 + l];
      else if (l < 40 && mode != 2) v = xe[(long long)rw*5 + (l-35)];
    }
    Aw[r*AST + l] = f2b(v);
  }

  // ---- backtracking correction (rare: ~16 edges total in the whole graph)
  if (mode == 1 && el > sl){
    for (int j=sl; j<el && j<CORR_CAP; j++){
      const u16* crow = corrbuf + (long long)j*HD + lq*8;
      #pragma unroll
      for (int ks=2; ks<10; ks++){
        bf16x8 cv = *(const bf16x8*)(crow + (ks-2)*32);
        #pragma unroll
        for (int i=0;i<8;i++)
          af[ks][i] = (short)f2b(b2f((u16)af[ks][i]) - b2f((u16)cv[i]));
      }
    }
  }

  // ---- feature frags from LDS (wave-private; no barrier needed)
  const u16* Ar = &A_lds[wave][lr][0];
  af[0] = *(const bf16x8*)(Ar + 0*32 + lq*8);
  af[1] = *(const bf16x8*)(Ar + 1*32 + lq*8);

  // ---- MFMA: frag-major B, fully coalesced loads
  f32x4 acc[16];
  #pragma unroll
  for (int nj=0;nj<16;nj++) acc[nj] = (f32x4){0.f,0.f,0.f,0.f};
  const u16* bb = BTf + l*8;

#define KSTEP(ks) { \
    _Pragma("unroll") \
    for (int nj=0;nj<16;nj++){ \
      bf16x8 bf = *(const bf16x8*)(bb + ((ks)*16+nj)*512); \
      acc[nj] = __builtin_amdgcn_mfma_f32_16x16x32_bf16(af[ks], bf, acc[nj], 0,0,0); \
    } }
  KSTEP(0) KSTEP(1)
  if (mode != 0){
    KSTEP(2) KSTEP(3) KSTEP(4) KSTEP(5)
    KSTEP(6) KSTEP(7) KSTEP(8) KSTEP(9)
  }
#undef KSTEP

  // ---- epilogue: C/D layout col=lr, row=lq*4+reg
  #pragma unroll
  for (int reg=0; reg<4; reg++){
    int gm = m0 + lq*4 + reg;
    if (gm < M){
      if (mode == 2){
        #pragma unroll
        for (int nj=0;nj<16;nj++){
          int col = nj*16 + lr;
          float v = acc[nj][reg] + bias[col];
          out32[(long long)gm*HD + col] = v > 0.f ? v : 0.f;
        }
      } else {
        #pragma unroll
        for (int nj=0;nj<16;nj++){
          int col = nj*16 + lr;
          float v = acc[nj][reg];
          out16[(long long)gm*HD + col] = f2b(v > 0.f ? v : 0.f);
        }
      }
    }
  }
}

// ---------------- graph mean (graph_ids sorted), fp32 in/out ----------------
__global__ void k_graph_mean(const float* __restrict__ h, const int* __restrict__ gid,
                             int N, int G, float* __restrict__ out){
  int g = (int)(((long long)blockIdx.x*blockDim.x + threadIdx.x)>>6);
  int l = threadIdx.x & 63;
  if (g >= G) return;
  int lo=0, hi=N;
  while (lo<hi){ int mid=(lo+hi)>>1; if (gid[mid] < g) lo=mid+1; else hi=mid; }
  int b = lo;
  hi = N;
  while (lo<hi){ int mid=(lo+hi)>>1; if (gid[mid] < g+1) lo=mid+1; else hi=mid; }
  int e2 = lo;
  float a0=0.f,a1=0.f,a2=0.f,a3=0.f;
  for (int v=b; v<e2; v++){
    float4 hv = *(const float4*)(h + (long long)v*HD + l*4);
    a0 += hv.x; a1 += hv.y; a2 += hv.z; a3 += hv.w;
  }
  int cnt = e2 - b; if (cnt < 1) cnt = 1;
  float inv = 1.0f/(float)cnt;
  float4 o; o.x=a0*inv; o.y=a1*inv; o.z=a2*inv; o.w=a3*inv;
  *(float4*)(out + (long long)g*HD + l*4) = o;
}

extern "C" void kernel_launch(void* const* d_in, const int* in_sizes, int n_in,
                              void* d_out, int out_size, void* d_ws, size_t ws_size,
                              hipStream_t stream){
  const float* x_nodes = (const float*)d_in[0];
  const float* x_edges = (const float*)d_in[1];
  const float* tree_m  = (const float*)d_in[2];
  const float* W_i     = (const float*)d_in[3];
  const float* W_h     = (const float*)d_in[4];
  const float* W_o     = (const float*)d_in[5];
  const float* b_o     = (const float*)d_in[6];
  const int* edge_src = (const int*)d_in[7];
  const int* edge_dst = (const int*)d_in[8];
  const int* tgt      = (const int*)d_in[11];
  const int* teid     = (const int*)d_in[12];
  const int* gid      = (const int*)d_in[13];

  const int N = in_sizes[0]/35;
  const int E = in_sizes[1]/5;
  const int K = in_sizes[11];
  const int G = out_size/HD;

  // ---- workspace layout (~163 MB footprint; single msg buffer, L3-resident set) ----
  char* wsb = (char*)d_ws;
  auto align256 = [](size_t x){ return (x + 255) & ~(size_t)255; };
  size_t oMsg    = 0;
  size_t oAlpha  = oMsg    + align256((size_t)E*HD*2);        // 102.4 MB
  size_t oNacc   = oAlpha  + align256((size_t)N*HD*2);        // 25.6 MB
  size_t oBTbp   = oNacc   + align256((size_t)N*HD*2);        // 25.6 MB
  size_t oBTfo   = oBTbp   + align256((size_t)81920*2);       // 160 KB
  size_t oCsrT   = oBTfo   + align256((size_t)81920*2);       // 160 KB
  // tgt-CSR
  size_t oDegT   = oCsrT;
  size_t oStartT = oDegT   + align256((size_t)N*4);
  size_t oCurT   = oStartT + align256((size_t)(N+1)*4);
  size_t oBukT   = oCurT   + align256((size_t)N*4);
  // dst-CSR
  size_t oDegD   = oBukT   + align256((size_t)K*4);
  size_t oStartD = oDegD   + align256((size_t)N*4);
  size_t oCurD   = oStartD + align256((size_t)(N+1)*4);
  size_t oBukD   = oCurD   + align256((size_t)N*4);
  // corr CSR + snapshot buffer
  size_t oDegC   = oBukD   + align256((size_t)E*4);
  size_t oStartC = oDegC   + align256((size_t)E*4);
  size_t oCurC   = oStartC + align256((size_t)(E+1)*4);
  size_t oEdgeC  = oCurC   + align256((size_t)E*4);
  size_t oCorrB  = oEdgeC  + align256((size_t)CORR_CAP*4);
  // (end = oCorrB + CORR_CAP*HD*2 ≈ 163 MB)

  u16*   msg     = (u16*)(wsb + oMsg);
  u16*   alpha16 = (u16*)(wsb + oAlpha);
  u16*   nacc    = (u16*)(wsb + oNacc);
  u16*   BTf_bp  = (u16*)(wsb + oBTbp);
  u16*   BTf_fo  = (u16*)(wsb + oBTfo);
  int*   deg_t   = (int*)(wsb + oDegT);
  int*   start_t = (int*)(wsb + oStartT);
  int*   cur_t   = (int*)(wsb + oCurT);
  int*   buk_t   = (int*)(wsb + oBukT);
  int*   deg_d   = (int*)(wsb + oDegD);
  int*   start_d = (int*)(wsb + oStartD);
  int*   cur_d   = (int*)(wsb + oCurD);
  int*   buk_d   = (int*)(wsb + oBukD);
  int*   deg_c   = (int*)(wsb + oDegC);
  int*   start_c = (int*)(wsb + oStartC);
  int*   cur_c   = (int*)(wsb + oCurC);
  int*   edge_c  = (int*)(wsb + oEdgeC);
  u16*   corrbuf = (u16*)(wsb + oCorrB);
  // hbuf overlays msg (msg dead after the final k_nodesum)
  float* hbuf    = (float*)(wsb + oMsg);                      // 51.2 MB

  const int ngrid    = (N+255)/256;
  const int egrid256 = (E+255)/256;
  const int kgrid256 = (K+255)/256;
  const int egrid    = (E+63)/64;

  k_prep_B<<<320, 256, 0, stream>>>(W_i, W_h, W_o, BTf_bp, BTf_fo);

  // tgt-CSR + alpha gather
  k_zero_int<<<ngrid, 256, 0, stream>>>(deg_t, N);
  k_hist<<<kgrid256, 256, 0, stream>>>(tgt, deg_t, K);
  k_scan<<<1, 1024, 0, stream>>>(deg_t, start_t, cur_t, N);
  k_fill<<<kgrid256, 256, 0, stream>>>(tgt, teid, cur_t, buk_t, K);
  k_alpha_gather<<<(N+3)/4, 256, 0, stream>>>(tree_m, start_t, buk_t, alpha16, N);

  // dst-CSR (needed up-front now: nodesum every iteration)
  k_zero_int<<<ngrid, 256, 0, stream>>>(deg_d, N);
  k_hist<<<egrid256, 256, 0, stream>>>(edge_dst, deg_d, E);
  k_scan<<<1, 1024, 0, stream>>>(deg_d, start_d, cur_d, N);
  k_fill<<<egrid256, 256, 0, stream>>>(edge_dst, (const int*)0, cur_d, buk_d, E);

  // backtracking-pair CSR (graph-constant)
  k_corr_count<<<egrid256, 256, 0, stream>>>(edge_src, edge_dst, start_d, buk_d, deg_c, E);
  k_scan<<<1, 1024, 0, stream>>>(deg_c, start_c, cur_c, E);
  k_corr_fill<<<egrid256, 256, 0, stream>>>(edge_src, edge_dst, start_d, buk_d, start_c, edge_c, E);

  // iter0: msg = relu([x_src|xe] @ Wi)
  k_mpnn<<<egrid, 256, 0, stream>>>(x_nodes, x_edges, (const u16*)0, (const u16*)0,
                                    (const int*)0, edge_src, BTf_bp, (const float*)0,
                                    msg, (float*)0, E, 0);
  // BP iters: nodeacc = segsum_dst(msg)+alpha; snapshot corr rows; msg updated in place
  for (int it=0; it<3; ++it){
    k_nodesum<<<(N+3)/4, 256, 0, stream>>>(msg, alpha16, start_d, buk_d, nacc, N);
    k_snapshot<<<CORR_CAP/4, 256, 0, stream>>>(msg, edge_c, start_c + E, corrbuf);
    k_mpnn<<<egrid, 256, 0, stream>>>(x_nodes, x_edges, nacc, corrbuf,
                                      start_c, edge_src, BTf_bp, (const float*)0,
                                      msg, (float*)0, E, 1);
  }
  // output layer: m + node_alpha == nodeacc(final msg); no gather in mode 2
  k_nodesum<<<(N+3)/4, 256, 0, stream>>>(msg, alpha16, start_d, buk_d, nacc, N);
  k_mpnn<<<(N+63)/64, 256, 0, stream>>>(x_nodes, (const float*)0, nacc, (const u16*)0,
                                        (const int*)0, (const int*)0, BTf_fo, b_o,
                                        (u16*)0, hbuf, N, 2);
  k_graph_mean<<<(G+3)/4, 256, 0, stream>>>(hbuf, gid, N, G, (float*)d_out);
}

// Round 2
// 1064.679 us; speedup vs baseline: 1.5858x; 1.5858x over previous
//
#include <hip/hip_runtime.h>
#include <stdint.h>

typedef unsigned short u16;
typedef __attribute__((ext_vector_type(8))) short bf16x8;
typedef __attribute__((ext_vector_type(4))) float f32x4;

#define HD 256
#define AST 72        // A_lds row stride in u16 (144 B; rotates banks row-to-row)
#define CORR_CAP 8192 // backtracking-pair capacity (expected ~16 for this graph)

static __device__ __forceinline__ float b2f(u16 x){
  union{float f; unsigned u;} v; v.u = ((unsigned)x)<<16; return v.f;
}
static __device__ __forceinline__ u16 f2b(float f){
  union{float f; unsigned u;} v; v.f = f;
  unsigned r = v.u + 0x7fffu + ((v.u>>16)&1u);
  return (u16)(r>>16);
}
static __device__ __forceinline__ void acc4(float* a, uint2 v){
  a[0] += b2f((u16)v.x); a[1] += b2f((u16)(v.x>>16));
  a[2] += b2f((u16)v.y); a[3] += b2f((u16)(v.y>>16));
}

// ---------------- zero int buffer ----------------
__global__ void k_zero_int(int* __restrict__ p, int n){
  int i = blockIdx.x*256 + threadIdx.x;
  if (i < n) p[i] = 0;
}

// ---------------- histogram ----------------
__global__ void k_hist(const int* __restrict__ key, int* __restrict__ deg, int n){
  int i = blockIdx.x*256 + threadIdx.x;
  if (i < n) atomicAdd(&deg[key[i]], 1);
}

// ---------------- 3-phase parallel exclusive scan ----------------
// p1: per-block (256-elem) sums
__global__ void k_scan_p1(const int* __restrict__ deg, int n, int* __restrict__ bsum){
  int i = blockIdx.x*256 + threadIdx.x;
  int v = (i < n) ? deg[i] : 0;
  #pragma unroll
  for (int o=32; o>0; o>>=1) v += __shfl_down(v, o);
  __shared__ int w[4];
  if ((threadIdx.x&63)==0) w[threadIdx.x>>6] = v;
  __syncthreads();
  if (threadIdx.x==0) bsum[blockIdx.x] = w[0]+w[1]+w[2]+w[3];
}
// p2: single-block exclusive scan of block sums (nb <= 1024); writes grand total
__global__ __launch_bounds__(1024) void k_scan_p2(int* __restrict__ bsum, int nb,
                                                  int* __restrict__ total_dst){
  __shared__ int sm[1024];
  int t = threadIdx.x;
  int v = (t < nb) ? bsum[t] : 0;
  sm[t] = v; __syncthreads();
  for (int o=1; o<1024; o<<=1){
    int u = (t>=o) ? sm[t-o] : 0;
    __syncthreads();
    sm[t] += u;
    __syncthreads();
  }
  if (t < nb) bsum[t] = sm[t] - v;
  if (t == 1023 && total_dst) *total_dst = sm[1023];
}
// p3: in-block exclusive scan + block base -> start, cursor
__global__ void k_scan_p3(const int* __restrict__ deg, const int* __restrict__ bsum, int n,
                          int* __restrict__ start, int* __restrict__ cursor){
  int t = threadIdx.x;
  int i = blockIdx.x*256 + t;
  int v = (i < n) ? deg[i] : 0;
  __shared__ int sm[256];
  sm[t] = v; __syncthreads();
  for (int o=1; o<256; o<<=1){
    int u = (t>=o) ? sm[t-o] : 0;
    __syncthreads();
    sm[t] += u;
    __syncthreads();
  }
  int ex = sm[t] - v + bsum[blockIdx.x];
  if (i < n){ start[i] = ex; cursor[i] = ex; }
}

// ---------------- fill buckets ----------------
__global__ void k_fill(const int* __restrict__ key, const int* __restrict__ val,
                       int* __restrict__ cursor, int* __restrict__ bucket, int n){
  int i = blockIdx.x*256 + threadIdx.x;
  if (i >= n) return;
  int pos = atomicAdd(&cursor[key[i]], 1);
  bucket[pos] = val ? val[i] : i;
}

// ---------------- alpha16[v] = bf16( sum_{j} tree_m[bucket[j]] ) ----------------
__global__ void k_alpha_gather(const float* __restrict__ tree_m, const int* __restrict__ start,
                               const int* __restrict__ bucket, u16* __restrict__ alpha16, int N){
  int v = (int)(((long long)blockIdx.x*blockDim.x + threadIdx.x)>>6);
  int l = threadIdx.x & 63;
  if (v >= N) return;
  int s = start[v], e2 = start[v+1];
  float a0=0.f,a1=0.f,a2=0.f,a3=0.f;
  for (int j=s;j<e2;j++){
    float4 tv = *(const float4*)(tree_m + (long long)bucket[j]*HD + l*4);
    a0 += tv.x; a1 += tv.y; a2 += tv.z; a3 += tv.w;
  }
  ushort4 o; o.x=f2b(a0); o.y=f2b(a1); o.z=f2b(a2); o.w=f2b(a3);
  *(ushort4*)(alpha16 + (long long)v*HD + l*4) = o;
}

// ---------------- nodeacc[v] = bf16( alpha[v] + sum_{e: dst[e]=v} msg[e] ) ----------------
__global__ void k_nodesum(const u16* __restrict__ msg, const u16* __restrict__ alpha16,
                          const int* __restrict__ start_d, const int* __restrict__ bucket_d,
                          u16* __restrict__ nodeacc, int N){
  int v = (int)(((long long)blockIdx.x*blockDim.x + threadIdx.x)>>6);
  int l = threadIdx.x & 63;
  if (v >= N) return;
  int s = start_d[v], e2 = start_d[v+1];
  float a[4];
  { uint2 av = *(const uint2*)(alpha16 + (long long)v*HD + l*4);
    a[0]=b2f((u16)av.x); a[1]=b2f((u16)(av.x>>16));
    a[2]=b2f((u16)av.y); a[3]=b2f((u16)(av.y>>16)); }
  const u16* ml = msg + l*4;
  int j = s;
  for (; j+4 <= e2; j+=4){
    int q0=bucket_d[j], q1=bucket_d[j+1], q2=bucket_d[j+2], q3=bucket_d[j+3];
    uint2 v0 = *(const uint2*)(ml + (long long)q0*HD);
    uint2 v1 = *(const uint2*)(ml + (long long)q1*HD);
    uint2 v2 = *(const uint2*)(ml + (long long)q2*HD);
    uint2 v3 = *(const uint2*)(ml + (long long)q3*HD);
    acc4(a, v0); acc4(a, v1); acc4(a, v2); acc4(a, v3);
  }
  for (; j < e2; j++){
    uint2 v0 = *(const uint2*)(ml + (long long)bucket_d[j]*HD);
    acc4(a, v0);
  }
  ushort4 o; o.x=f2b(a[0]); o.y=f2b(a[1]); o.z=f2b(a[2]); o.w=f2b(a[3]);
  *(ushort4*)(nodeacc + (long long)v*HD + l*4) = o;
}

// ---------------- backtracking pair list (compact, atomic append) ----------------
// pair (e, ep): dst[ep]==src[e] && src[ep]==dst[e]  (~16 expected total)
__global__ void k_pairs(const int* __restrict__ esrc, const int* __restrict__ edst,
                        const int* __restrict__ start_d, const int* __restrict__ bucket_d,
                        int* __restrict__ npairs, int2* __restrict__ pairs, int E){
  int e = blockIdx.x*256 + threadIdx.x;
  if (e >= E) return;
  int u = esrc[e], v = edst[e];
  int s = start_d[u], t = start_d[u+1];
  for (int j=s;j<t;j++){
    int ep = bucket_d[j];
    if (esrc[ep] == v){
      int pos = atomicAdd(npairs, 1);
      if (pos < CORR_CAP) pairs[pos] = (int2){e, ep};
    }
  }
}

// snapshot old msg rows of pair partners before in-place msg overwrite
__global__ void k_snapshot(const u16* __restrict__ msg, const int2* __restrict__ pairs,
                           const int* __restrict__ npairs_p, u16* __restrict__ corrbuf){
  int np = *npairs_p; if (np > CORR_CAP) np = CORR_CAP;
  int wid = (blockIdx.x*256 + threadIdx.x) >> 6;
  int l = threadIdx.x & 63;
  int nw = gridDim.x * 4;
  for (int p = wid; p < np; p += nw){
    int ep = pairs[p].y;
    *(uint2*)(corrbuf + (long long)p*HD + l*4) =
        *(const uint2*)(msg + (long long)ep*HD + l*4);
  }
}

// exact fp32 recompute of the (rare) backtracking-affected msg rows, overwrite after GEMM
__global__ __launch_bounds__(256) void k_fixup(
    const float* __restrict__ xn, const float* __restrict__ xe, const int* __restrict__ esrc,
    const u16* __restrict__ nacc, const u16* __restrict__ corrbuf,
    const int2* __restrict__ pairs, const int* __restrict__ npairs_p,
    const float* __restrict__ Wi, const float* __restrict__ Wh, u16* __restrict__ msg){
  int np = *npairs_p; if (np > CORR_CAP) np = CORR_CAP;
  int t = threadIdx.x;
  __shared__ float cs[256];
  for (int p = blockIdx.x; p < np; p += gridDim.x){
    int e = pairs[p].x;
    bool first = true;
    for (int q=0;q<p;q++) if (pairs[q].x == e){ first = false; break; }
    if (!first) continue;                 // block-uniform branch
    int u = esrc[e];
    float c = 0.f;
    for (int q=p;q<np;q++) if (pairs[q].x == e) c += b2f(corrbuf[(long long)q*HD + t]);
    cs[t] = c; __syncthreads();
    float acc = 0.f;
    for (int k=0;k<35;k++) acc += xn[(long long)u*35 + k] * Wi[k*HD + t];
    for (int k=0;k<5;k++)  acc += xe[(long long)e*5  + k] * Wi[(35+k)*HD + t];
    for (int k=0;k<HD;k++) acc += (b2f(nacc[(long long)u*HD + k]) - cs[k]) * Wh[k*HD + t];
    msg[(long long)e*HD + t] = f2b(acc > 0.f ? acc : 0.f);
    __syncthreads();
  }
}

// ---------------- frag-major B prep ----------------
__global__ void k_prep_B(const float* __restrict__ Wi, const float* __restrict__ Wh,
                         const float* __restrict__ Wo,
                         u16* __restrict__ BTf_bp, u16* __restrict__ BTf_fo){
  int g = blockIdx.x*256 + threadIdx.x;   // 81920 total
  if (g >= 81920) return;
  int i = g & 7;
  int l = (g>>3) & 63;
  int t = g >> 9;                // 0..159
  int nj = t & 15, ks = t >> 4;  // ks 0..9
  int n = nj*16 + (l & 15);
  int k = ks*32 + (l>>4)*8 + i;
  float bp = 0.f, fo = 0.f;
  if (k < 40) bp = Wi[k*HD + n];
  else if (k >= 64) bp = Wh[(k-64)*HD + n];
  if (k < 35) fo = Wo[k*HD + n];
  else if (k >= 64) fo = Wo[(k-29)*HD + n];
  BTf_bp[g] = f2b(bp);
  BTf_fo[g] = f2b(fo);
}

// ---------------- fused MPNN GEMM, wave-per-16-rows ----------------
// mode 0: A=[x_src|xe|0], ksteps 2
// mode 1: A=[x_src|xe| nodeacc[src] ], ksteps 10 (out16, in-place msg; corr via k_fixup)
// mode 2: A=[x_node|0| nodeacc[row] ], ksteps 10 (out32, +bias)
__global__ __launch_bounds__(256, 3) void k_mpnn(
    const float* __restrict__ xn, const float* __restrict__ xe,
    const u16* __restrict__ nacc, const int* __restrict__ esrc,
    const u16* __restrict__ BTf, const float* __restrict__ bias,
    u16* __restrict__ out16, float* __restrict__ out32, int M, int mode)
{
  __shared__ u16 A_lds[4][16][AST];   // 9,216 B
  const int tid = threadIdx.x;
  const int wave = tid>>6, l = tid&63;
  const int lr = l&15, lq = l>>4;
  const int m0 = blockIdx.x*64 + wave*16;
  u16* Aw = &A_lds[wave][0][0];

  const int rowl = m0 + lr;
  const bool rvl = rowl < M;
  int srcl = 0;
  if (rvl) srcl = (mode==2) ? rowl : esrc[rowl];

  // ---- direct A-frags for cols [64,320): issue early to hide latency
  bf16x8 af[10];
  if (mode != 0){
    const u16* nrow = nacc + (long long)srcl*HD + lq*8;
    #pragma unroll
    for (int ks=2; ks<10; ks++)
      af[ks] = *(const bf16x8*)(nrow + (ks-2)*32);
  }

  // ---- stage features cols [0,64): coalesced per-row loads via LDS transpose
  for (int r=0; r<16; r++){
    int sv = __shfl(srcl, r);
    int rw = m0 + r;
    float v = 0.f;
    if (rw < M){
      if (l < 35) v = xn[(long long)sv*35 + l];
      else if (l < 40 && mode != 2) v = xe[(long long)rw*5 + (l-35)];
    }
    Aw[r*AST + l] = f2b(v);
  }

  // ---- feature frags from LDS (wave-private; no barrier needed)
  const u16* Ar = &A_lds[wave][lr][0];
  af[0] = *(const bf16x8*)(Ar + 0*32 + lq*8);
  af[1] = *(const bf16x8*)(Ar + 1*32 + lq*8);

  // ---- MFMA: frag-major B, fully coalesced loads
  f32x4 acc[16];
  #pragma unroll
  for (int nj=0;nj<16;nj++) acc[nj] = (f32x4){0.f,0.f,0.f,0.f};
  const u16* bb = BTf + l*8;

#define KSTEP(ks) { \
    _Pragma("unroll") \
    for (int nj=0;nj<16;nj++){ \
      bf16x8 bf = *(const bf16x8*)(bb + ((ks)*16+nj)*512); \
      acc[nj] = __builtin_amdgcn_mfma_f32_16x16x32_bf16(af[ks], bf, acc[nj], 0,0,0); \
    } }
  KSTEP(0) KSTEP(1)
  if (mode != 0){
    KSTEP(2) KSTEP(3) KSTEP(4) KSTEP(5)
    KSTEP(6) KSTEP(7) KSTEP(8) KSTEP(9)
  }
#undef KSTEP

  // ---- epilogue: C/D layout col=lr, row=lq*4+reg
  #pragma unroll
  for (int reg=0; reg<4; reg++){
    int gm = m0 + lq*4 + reg;
    if (gm < M){
      if (mode == 2){
        #pragma unroll
        for (int nj=0;nj<16;nj++){
          int col = nj*16 + lr;
          float v = acc[nj][reg] + bias[col];
          out32[(long long)gm*HD + col] = v > 0.f ? v : 0.f;
        }
      } else {
        #pragma unroll
        for (int nj=0;nj<16;nj++){
          int col = nj*16 + lr;
          float v = acc[nj][reg];
          out16[(long long)gm*HD + col] = f2b(v > 0.f ? v : 0.f);
        }
      }
    }
  }
}

// ---------------- graph mean (graph_ids sorted), fp32 in/out ----------------
__global__ void k_graph_mean(const float* __restrict__ h, const int* __restrict__ gid,
                             int N, int G, float* __restrict__ out){
  int g = (int)(((long long)blockIdx.x*blockDim.x + threadIdx.x)>>6);
  int l = threadIdx.x & 63;
  if (g >= G) return;
  int lo=0, hi=N;
  while (lo<hi){ int mid=(lo+hi)>>1; if (gid[mid] < g) lo=mid+1; else hi=mid; }
  int b = lo;
  hi = N;
  while (lo<hi){ int mid=(lo+hi)>>1; if (gid[mid] < g+1) lo=mid+1; else hi=mid; }
  int e2 = lo;
  float a0=0.f,a1=0.f,a2=0.f,a3=0.f;
  for (int v=b; v<e2; v++){
    float4 hv = *(const float4*)(h + (long long)v*HD + l*4);
    a0 += hv.x; a1 += hv.y; a2 += hv.z; a3 += hv.w;
  }
  int cnt = e2 - b; if (cnt < 1) cnt = 1;
  float inv = 1.0f/(float)cnt;
  float4 o; o.x=a0*inv; o.y=a1*inv; o.z=a2*inv; o.w=a3*inv;
  *(float4*)(out + (long long)g*HD + l*4) = o;
}

extern "C" void kernel_launch(void* const* d_in, const int* in_sizes, int n_in,
                              void* d_out, int out_size, void* d_ws, size_t ws_size,
                              hipStream_t stream){
  const float* x_nodes = (const float*)d_in[0];
  const float* x_edges = (const float*)d_in[1];
  const float* tree_m  = (const float*)d_in[2];
  const float* W_i     = (const float*)d_in[3];
  const float* W_h     = (const float*)d_in[4];
  const float* W_o     = (const float*)d_in[5];
  const float* b_o     = (const float*)d_in[6];
  const int* edge_src = (const int*)d_in[7];
  const int* edge_dst = (const int*)d_in[8];
  const int* tgt      = (const int*)d_in[11];
  const int* teid     = (const int*)d_in[12];
  const int* gid      = (const int*)d_in[13];

  const int N = in_sizes[0]/35;
  const int E = in_sizes[1]/5;
  const int K = in_sizes[11];
  const int G = out_size/HD;
  const int N2 = 2*N;

  // ---- workspace layout (~160 MB footprint) ----
  char* wsb = (char*)d_ws;
  auto align256 = [](size_t x){ return (x + 255) & ~(size_t)255; };
  size_t oMsg    = 0;
  size_t oAlpha  = oMsg    + align256((size_t)E*HD*2);        // 102.4 MB
  size_t oNacc   = oAlpha  + align256((size_t)N*HD*2);        // 25.6 MB
  size_t oBTbp   = oNacc   + align256((size_t)N*HD*2);        // 25.6 MB
  size_t oBTfo   = oBTbp   + align256((size_t)81920*2);       // 160 KB
  size_t oDeg2   = oBTfo   + align256((size_t)81920*2);       // (2N+1) ints; [2N]=npairs
  size_t oStart2 = oDeg2   + align256((size_t)(N2+1)*4);      // 2N+1 ints
  size_t oCur2   = oStart2 + align256((size_t)(N2+1)*4);      // 2N ints
  size_t oBuk2   = oCur2   + align256((size_t)N2*4);          // K+E ints
  size_t oBsum   = oBuk2   + align256((size_t)(K+E)*4);       // 1024 ints
  size_t oPairs  = oBsum   + align256((size_t)1024*4);        // CORR_CAP int2
  size_t oCorrB  = oPairs  + align256((size_t)CORR_CAP*8);    // 4 MB

  u16*   msg     = (u16*)(wsb + oMsg);
  u16*   alpha16 = (u16*)(wsb + oAlpha);
  u16*   nacc    = (u16*)(wsb + oNacc);
  u16*   BTf_bp  = (u16*)(wsb + oBTbp);
  u16*   BTf_fo  = (u16*)(wsb + oBTfo);
  int*   deg2    = (int*)(wsb + oDeg2);
  int*   npairs  = deg2 + N2;               // zeroed together with deg2
  int*   start2  = (int*)(wsb + oStart2);
  int*   cursor2 = (int*)(wsb + oCur2);
  int*   bucket2 = (int*)(wsb + oBuk2);
  int*   bsum    = (int*)(wsb + oBsum);
  int2*  pairs   = (int2*)(wsb + oPairs);
  u16*   corrbuf = (u16*)(wsb + oCorrB);
  // hbuf overlays msg (msg dead after the final k_nodesum)
  float* hbuf    = (float*)(wsb + oMsg);                      // 51.2 MB

  const int egrid256 = (E+255)/256;
  const int kgrid256 = (K+255)/256;
  const int egrid    = (E+63)/64;
  const int nb       = (N2+255)/256;   // scan blocks (<=1024)

  k_prep_B<<<320, 256, 0, stream>>>(W_i, W_h, W_o, BTf_bp, BTf_fo);

  // concatenated histograms: deg2=[deg_tgt | deg_dst] (+ npairs slot zeroed)
  k_zero_int<<<(N2+1+255)/256, 256, 0, stream>>>(deg2, N2+1);
  k_hist<<<kgrid256, 256, 0, stream>>>(tgt, deg2, K);
  k_hist<<<egrid256, 256, 0, stream>>>(edge_dst, deg2 + N, E);

  // one parallel scan over 2N -> start2/cursor2 (positions into concatenated bucket2)
  k_scan_p1<<<nb, 256, 0, stream>>>(deg2, N2, bsum);
  k_scan_p2<<<1, 1024, 0, stream>>>(bsum, nb, start2 + N2);   // start2[2N] = K+E
  k_scan_p3<<<nb, 256, 0, stream>>>(deg2, bsum, N2, start2, cursor2);

  k_fill<<<kgrid256, 256, 0, stream>>>(tgt, teid, cursor2, bucket2, K);
  k_fill<<<egrid256, 256, 0, stream>>>(edge_dst, (const int*)0, cursor2 + N, bucket2, E);

  k_alpha_gather<<<(N+3)/4, 256, 0, stream>>>(tree_m, start2, bucket2, alpha16, N);
  k_pairs<<<egrid256, 256, 0, stream>>>(edge_src, edge_dst, start2 + N, bucket2,
                                        npairs, pairs, E);

  // iter0: msg = relu([x_src|xe] @ Wi)
  k_mpnn<<<egrid, 256, 0, stream>>>(x_nodes, x_edges, (const u16*)0, edge_src,
                                    BTf_bp, (const float*)0, msg, (float*)0, E, 0);
  // BP iters: nodeacc = segsum_dst(msg)+alpha; snapshot pair rows; in-place GEMM; fixup
  for (int it=0; it<3; ++it){
    k_nodesum<<<(N+3)/4, 256, 0, stream>>>(msg, alpha16, start2 + N, bucket2, nacc, N);
    k_snapshot<<<32, 256, 0, stream>>>(msg, pairs, npairs, corrbuf);
    k_mpnn<<<egrid, 256, 0, stream>>>(x_nodes, x_edges, nacc, edge_src,
                                      BTf_bp, (const float*)0, msg, (float*)0, E, 1);
    k_fixup<<<64, 256, 0, stream>>>(x_nodes, x_edges, edge_src, nacc, corrbuf,
                                    pairs, npairs, W_i, W_h, msg);
  }
  // output layer: m + node_alpha == nodeacc(final msg)
  k_nodesum<<<(N+3)/4, 256, 0, stream>>>(msg, alpha16, start2 + N, bucket2, nacc, N);
  k_mpnn<<<(N+63)/64, 256, 0, stream>>>(x_nodes, (const float*)0, nacc, (const int*)0,
                                        BTf_fo, b_o, (u16*)0, hbuf, N, 2);
  k_graph_mean<<<(G+3)/4, 256, 0, stream>>>(hbuf, gid, N, G, (float*)d_out);
}

// Round 3
// 1022.394 us; speedup vs baseline: 1.6514x; 1.0414x over previous
//
#include <hip/hip_runtime.h>
#include <stdint.h>

typedef unsigned short u16;
typedef __attribute__((ext_vector_type(8))) short bf16x8;
typedef __attribute__((ext_vector_type(4))) float f32x4;

#define HD 256
#define CORR_CAP 8192 // backtracking-pair capacity (expected ~16 for this graph)

static __device__ __forceinline__ float b2f(u16 x){
  union{float f; unsigned u;} v; v.u = ((unsigned)x)<<16; return v.f;
}
static __device__ __forceinline__ u16 f2b(float f){
  union{float f; unsigned u;} v; v.f = f;
  unsigned r = v.u + 0x7fffu + ((v.u>>16)&1u);
  return (u16)(r>>16);
}
static __device__ __forceinline__ void acc4(float* a, uint2 v){
  a[0] += b2f((u16)v.x); a[1] += b2f((u16)(v.x>>16));
  a[2] += b2f((u16)v.y); a[3] += b2f((u16)(v.y>>16));
}

// ---------------- zero int buffer ----------------
__global__ void k_zero_int(int* __restrict__ p, int n){
  int i = blockIdx.x*256 + threadIdx.x;
  if (i < n) p[i] = 0;
}

// ---------------- histogram ----------------
__global__ void k_hist(const int* __restrict__ key, int* __restrict__ deg, int n){
  int i = blockIdx.x*256 + threadIdx.x;
  if (i < n) atomicAdd(&deg[key[i]], 1);
}

// ---------------- 3-phase parallel exclusive scan ----------------
__global__ void k_scan_p1(const int* __restrict__ deg, int n, int* __restrict__ bsum){
  int i = blockIdx.x*256 + threadIdx.x;
  int v = (i < n) ? deg[i] : 0;
  #pragma unroll
  for (int o=32; o>0; o>>=1) v += __shfl_down(v, o);
  __shared__ int w[4];
  if ((threadIdx.x&63)==0) w[threadIdx.x>>6] = v;
  __syncthreads();
  if (threadIdx.x==0) bsum[blockIdx.x] = w[0]+w[1]+w[2]+w[3];
}
__global__ __launch_bounds__(1024) void k_scan_p2(int* __restrict__ bsum, int nb,
                                                  int* __restrict__ total_dst){
  __shared__ int sm[1024];
  int t = threadIdx.x;
  int v = (t < nb) ? bsum[t] : 0;
  sm[t] = v; __syncthreads();
  for (int o=1; o<1024; o<<=1){
    int u = (t>=o) ? sm[t-o] : 0;
    __syncthreads();
    sm[t] += u;
    __syncthreads();
  }
  if (t < nb) bsum[t] = sm[t] - v;
  if (t == 1023 && total_dst) *total_dst = sm[1023];
}
__global__ void k_scan_p3(const int* __restrict__ deg, const int* __restrict__ bsum, int n,
                          int* __restrict__ start, int* __restrict__ cursor){
  int t = threadIdx.x;
  int i = blockIdx.x*256 + t;
  int v = (i < n) ? deg[i] : 0;
  __shared__ int sm[256];
  sm[t] = v; __syncthreads();
  for (int o=1; o<256; o<<=1){
    int u = (t>=o) ? sm[t-o] : 0;
    __syncthreads();
    sm[t] += u;
    __syncthreads();
  }
  int ex = sm[t] - v + bsum[blockIdx.x];
  if (i < n){ start[i] = ex; cursor[i] = ex; }
}

// ---------------- fill buckets ----------------
__global__ void k_fill(const int* __restrict__ key, const int* __restrict__ val,
                       int* __restrict__ cursor, int* __restrict__ bucket, int n){
  int i = blockIdx.x*256 + threadIdx.x;
  if (i >= n) return;
  int pos = atomicAdd(&cursor[key[i]], 1);
  bucket[pos] = val ? val[i] : i;
}

// ---------------- alpha16[v] = bf16( sum_{j} tree_m[bucket[j]] ) ----------------
__global__ void k_alpha_gather(const float* __restrict__ tree_m, const int* __restrict__ start,
                               const int* __restrict__ bucket, u16* __restrict__ alpha16, int N){
  int v = (int)(((long long)blockIdx.x*blockDim.x + threadIdx.x)>>6);
  int l = threadIdx.x & 63;
  if (v >= N) return;
  int s = start[v], e2 = start[v+1];
  float a0=0.f,a1=0.f,a2=0.f,a3=0.f;
  for (int j=s;j<e2;j++){
    float4 tv = *(const float4*)(tree_m + (long long)bucket[j]*HD + l*4);
    a0 += tv.x; a1 += tv.y; a2 += tv.z; a3 += tv.w;
  }
  ushort4 o; o.x=f2b(a0); o.y=f2b(a1); o.z=f2b(a2); o.w=f2b(a3);
  *(ushort4*)(alpha16 + (long long)v*HD + l*4) = o;
}

// ---------------- A-row prefix tables (one-time) ----------------
// feat_e[e][64] = [ xn[src[e]] (35) | xe[e] (5) | 0 pad ]  (bf16)
__global__ void k_feat_e(const float* __restrict__ xn, const float* __restrict__ xe,
                         const int* __restrict__ esrc, u16* __restrict__ feat, int E){
  int g = blockIdx.x*256 + threadIdx.x;
  int e = g >> 6, c = g & 63;
  if (e >= E) return;
  float v = 0.f;
  if (c < 35) v = xn[(long long)esrc[e]*35 + c];
  else if (c < 40) v = xe[(long long)e*5 + (c-35)];
  feat[g] = f2b(v);
}
// xnf[v][64] = [ xn[v] (35) | 0 pad ]  (bf16)
__global__ void k_xnf(const float* __restrict__ xn, u16* __restrict__ xnf, int N){
  int g = blockIdx.x*256 + threadIdx.x;
  int v2 = g >> 6, c = g & 63;
  if (v2 >= N) return;
  float v = (c < 35) ? xn[(long long)v2*35 + c] : 0.f;
  xnf[g] = f2b(v);
}

// ---------------- nodeacc[v] = bf16( alpha[v] + sum_{e: dst[e]=v} msg[e] ) ----------------
__global__ void k_nodesum(const u16* __restrict__ msg, const u16* __restrict__ alpha16,
                          const int* __restrict__ start_d, const int* __restrict__ bucket_d,
                          u16* __restrict__ nodeacc, int N){
  int v = (int)(((long long)blockIdx.x*blockDim.x + threadIdx.x)>>6);
  int l = threadIdx.x & 63;
  if (v >= N) return;
  int s = start_d[v], e2 = start_d[v+1];
  float a[4];
  { uint2 av = *(const uint2*)(alpha16 + (long long)v*HD + l*4);
    a[0]=b2f((u16)av.x); a[1]=b2f((u16)(av.x>>16));
    a[2]=b2f((u16)av.y); a[3]=b2f((u16)(av.y>>16)); }
  const u16* ml = msg + l*4;
  int j = s;
  for (; j+4 <= e2; j+=4){
    int q0=bucket_d[j], q1=bucket_d[j+1], q2=bucket_d[j+2], q3=bucket_d[j+3];
    uint2 v0 = *(const uint2*)(ml + (long long)q0*HD);
    uint2 v1 = *(const uint2*)(ml + (long long)q1*HD);
    uint2 v2 = *(const uint2*)(ml + (long long)q2*HD);
    uint2 v3 = *(const uint2*)(ml + (long long)q3*HD);
    acc4(a, v0); acc4(a, v1); acc4(a, v2); acc4(a, v3);
  }
  for (; j < e2; j++){
    uint2 v0 = *(const uint2*)(ml + (long long)bucket_d[j]*HD);
    acc4(a, v0);
  }
  ushort4 o; o.x=f2b(a[0]); o.y=f2b(a[1]); o.z=f2b(a[2]); o.w=f2b(a[3]);
  *(ushort4*)(nodeacc + (long long)v*HD + l*4) = o;
}

// ---------------- backtracking pair list (compact, atomic append) ----------------
__global__ void k_pairs(const int* __restrict__ esrc, const int* __restrict__ edst,
                        const int* __restrict__ start_d, const int* __restrict__ bucket_d,
                        int* __restrict__ npairs, int2* __restrict__ pairs, int E){
  int e = blockIdx.x*256 + threadIdx.x;
  if (e >= E) return;
  int u = esrc[e], v = edst[e];
  int s = start_d[u], t = start_d[u+1];
  for (int j=s;j<t;j++){
    int ep = bucket_d[j];
    if (esrc[ep] == v){
      int pos = atomicAdd(npairs, 1);
      if (pos < CORR_CAP) pairs[pos] = (int2){e, ep};
    }
  }
}

// snapshot old msg rows of pair partners before in-place msg overwrite
__global__ void k_snapshot(const u16* __restrict__ msg, const int2* __restrict__ pairs,
                           const int* __restrict__ npairs_p, u16* __restrict__ corrbuf){
  int np = *npairs_p; if (np > CORR_CAP) np = CORR_CAP;
  int wid = (blockIdx.x*256 + threadIdx.x) >> 6;
  int l = threadIdx.x & 63;
  int nw = gridDim.x * 4;
  for (int p = wid; p < np; p += nw){
    int ep = pairs[p].y;
    *(uint2*)(corrbuf + (long long)p*HD + l*4) =
        *(const uint2*)(msg + (long long)ep*HD + l*4);
  }
}

// exact fp32 recompute of the (rare) backtracking-affected msg rows, overwrite after GEMM
__global__ __launch_bounds__(256) void k_fixup(
    const float* __restrict__ xn, const float* __restrict__ xe, const int* __restrict__ esrc,
    const u16* __restrict__ nacc, const u16* __restrict__ corrbuf,
    const int2* __restrict__ pairs, const int* __restrict__ npairs_p,
    const float* __restrict__ Wi, const float* __restrict__ Wh, u16* __restrict__ msg){
  int np = *npairs_p; if (np > CORR_CAP) np = CORR_CAP;
  int t = threadIdx.x;
  __shared__ float cs[256];
  for (int p = blockIdx.x; p < np; p += gridDim.x){
    int e = pairs[p].x;
    bool first = true;
    for (int q=0;q<p;q++) if (pairs[q].x == e){ first = false; break; }
    if (!first) continue;                 // block-uniform branch
    int u = esrc[e];
    float c = 0.f;
    for (int q=p;q<np;q++) if (pairs[q].x == e) c += b2f(corrbuf[(long long)q*HD + t]);
    cs[t] = c; __syncthreads();
    float acc = 0.f;
    for (int k=0;k<35;k++) acc += xn[(long long)u*35 + k] * Wi[k*HD + t];
    for (int k=0;k<5;k++)  acc += xe[(long long)e*5  + k] * Wi[(35+k)*HD + t];
    for (int k=0;k<HD;k++) acc += (b2f(nacc[(long long)u*HD + k]) - cs[k]) * Wh[k*HD + t];
    msg[(long long)e*HD + t] = f2b(acc > 0.f ? acc : 0.f);
    __syncthreads();
  }
}

// ---------------- frag-major B prep ----------------
__global__ void k_prep_B(const float* __restrict__ Wi, const float* __restrict__ Wh,
                         const float* __restrict__ Wo,
                         u16* __restrict__ BTf_bp, u16* __restrict__ BTf_fo){
  int g = blockIdx.x*256 + threadIdx.x;   // 81920 total
  if (g >= 81920) return;
  int i = g & 7;
  int l = (g>>3) & 63;
  int t = g >> 9;                // 0..159
  int nj = t & 15, ks = t >> 4;  // ks 0..9
  int n = nj*16 + (l & 15);
  int k = ks*32 + (l>>4)*8 + i;
  float bp = 0.f, fo = 0.f;
  if (k < 40) bp = Wi[k*HD + n];
  else if (k >= 64) bp = Wh[(k-64)*HD + n];
  if (k < 35) fo = Wo[k*HD + n];
  else if (k >= 64) fo = Wo[(k-29)*HD + n];
  BTf_bp[g] = f2b(bp);
  BTf_fo[g] = f2b(fo);
}

// ---------------- fused MPNN GEMM, wave-per-16-rows, all-direct A-frags ----------------
// featA: [M][64] bf16 prefix rows (mode0/1: feat_e; mode2: xnf)
// mode 0: A=[featA[row]|0], ksteps 2
// mode 1: A=[featA[row]| nacc[esrc[row]] ], ksteps 10 (out16, in-place msg)
// mode 2: A=[featA[row]| nacc[row] ], ksteps 10 (out32, +bias)
__global__ __launch_bounds__(256, 4) void k_mpnn(
    const u16* __restrict__ featA,
    const u16* __restrict__ nacc, const int* __restrict__ esrc,
    const u16* __restrict__ BTf, const float* __restrict__ bias,
    u16* __restrict__ out16, float* __restrict__ out32, int M, int mode)
{
  const int tid = threadIdx.x;
  const int wave = tid>>6, l = tid&63;
  const int lr = l&15, lq = l>>4;
  const int m0 = blockIdx.x*64 + wave*16;
  const int rowl = m0 + lr;
  const bool rvl = rowl < M;
  const int rowc = rvl ? rowl : 0;
  const int srcl = rvl ? ((mode==1) ? esrc[rowl] : rowl) : 0;

  bf16x8 af[10];
  // gather k-steps 2..9 first (longest latency)
  if (mode != 0){
    const u16* nrow = nacc + (long long)srcl*HD + lq*8;
    #pragma unroll
    for (int ks=2; ks<10; ks++)
      af[ks] = *(const bf16x8*)(nrow + (ks-2)*32);
  }
  // contiguous feature prefix (k-steps 0..1)
  {
    const u16* frow = featA + (long long)rowc*64 + lq*8;
    af[0] = *(const bf16x8*)(frow);
    af[1] = *(const bf16x8*)(frow + 32);
  }

  f32x4 acc[16];
  #pragma unroll
  for (int nj=0;nj<16;nj++) acc[nj] = (f32x4){0.f,0.f,0.f,0.f};
  const u16* bb = BTf + l*8;

#define KSTEP(ks) { \
    _Pragma("unroll") \
    for (int nj=0;nj<16;nj++){ \
      bf16x8 bf = *(const bf16x8*)(bb + ((ks)*16+nj)*512); \
      acc[nj] = __builtin_amdgcn_mfma_f32_16x16x32_bf16(af[ks], bf, acc[nj], 0,0,0); \
    } }
  KSTEP(0) KSTEP(1)
  if (mode != 0){
    KSTEP(2) KSTEP(3) KSTEP(4) KSTEP(5)
    KSTEP(6) KSTEP(7) KSTEP(8) KSTEP(9)
  }
#undef KSTEP

  // ---- epilogue: C/D layout col=lr, row=lq*4+reg
  #pragma unroll
  for (int reg=0; reg<4; reg++){
    int gm = m0 + lq*4 + reg;
    if (gm < M){
      if (mode == 2){
        #pragma unroll
        for (int nj=0;nj<16;nj++){
          int col = nj*16 + lr;
          float v = acc[nj][reg] + bias[col];
          out32[(long long)gm*HD + col] = v > 0.f ? v : 0.f;
        }
      } else {
        #pragma unroll
        for (int nj=0;nj<16;nj++){
          int col = nj*16 + lr;
          float v = acc[nj][reg];
          out16[(long long)gm*HD + col] = f2b(v > 0.f ? v : 0.f);
        }
      }
    }
  }
}

// ---------------- graph mean (graph_ids sorted), fp32 in/out ----------------
__global__ void k_graph_mean(const float* __restrict__ h, const int* __restrict__ gid,
                             int N, int G, float* __restrict__ out){
  int g = (int)(((long long)blockIdx.x*blockDim.x + threadIdx.x)>>6);
  int l = threadIdx.x & 63;
  if (g >= G) return;
  int lo=0, hi=N;
  while (lo<hi){ int mid=(lo+hi)>>1; if (gid[mid] < g) lo=mid+1; else hi=mid; }
  int b = lo;
  hi = N;
  while (lo<hi){ int mid=(lo+hi)>>1; if (gid[mid] < g+1) lo=mid+1; else hi=mid; }
  int e2 = lo;
  float a0=0.f,a1=0.f,a2=0.f,a3=0.f;
  for (int v=b; v<e2; v++){
    float4 hv = *(const float4*)(h + (long long)v*HD + l*4);
    a0 += hv.x; a1 += hv.y; a2 += hv.z; a3 += hv.w;
  }
  int cnt = e2 - b; if (cnt < 1) cnt = 1;
  float inv = 1.0f/(float)cnt;
  float4 o; o.x=a0*inv; o.y=a1*inv; o.z=a2*inv; o.w=a3*inv;
  *(float4*)(out + (long long)g*HD + l*4) = o;
}

extern "C" void kernel_launch(void* const* d_in, const int* in_sizes, int n_in,
                              void* d_out, int out_size, void* d_ws, size_t ws_size,
                              hipStream_t stream){
  const float* x_nodes = (const float*)d_in[0];
  const float* x_edges = (const float*)d_in[1];
  const float* tree_m  = (const float*)d_in[2];
  const float* W_i     = (const float*)d_in[3];
  const float* W_h     = (const float*)d_in[4];
  const float* W_o     = (const float*)d_in[5];
  const float* b_o     = (const float*)d_in[6];
  const int* edge_src = (const int*)d_in[7];
  const int* edge_dst = (const int*)d_in[8];
  const int* tgt      = (const int*)d_in[11];
  const int* teid     = (const int*)d_in[12];
  const int* gid      = (const int*)d_in[13];

  const int N = in_sizes[0]/35;
  const int E = in_sizes[1]/5;
  const int K = in_sizes[11];
  const int G = out_size/HD;
  const int N2 = 2*N;

  // ---- workspace layout (~193 MB footprint) ----
  char* wsb = (char*)d_ws;
  auto align256 = [](size_t x){ return (x + 255) & ~(size_t)255; };
  size_t oMsg    = 0;
  size_t oAlpha  = oMsg    + align256((size_t)E*HD*2);        // 102.4 MB
  size_t oNacc   = oAlpha  + align256((size_t)N*HD*2);        // 25.6 MB
  size_t oFeatE  = oNacc   + align256((size_t)N*HD*2);        // 25.6 MB
  size_t oXnf    = oFeatE  + align256((size_t)E*64*2);        // 25.6 MB
  size_t oBTbp   = oXnf    + align256((size_t)N*64*2);        // 6.4 MB
  size_t oBTfo   = oBTbp   + align256((size_t)81920*2);       // 160 KB
  size_t oDeg2   = oBTfo   + align256((size_t)81920*2);
  size_t oStart2 = oDeg2   + align256((size_t)(N2+1)*4);
  size_t oCur2   = oStart2 + align256((size_t)(N2+1)*4);
  size_t oBuk2   = oCur2   + align256((size_t)N2*4);
  size_t oBsum   = oBuk2   + align256((size_t)(K+E)*4);
  size_t oPairs  = oBsum   + align256((size_t)1024*4);
  size_t oCorrB  = oPairs  + align256((size_t)CORR_CAP*8);    // 4 MB

  u16*   msg     = (u16*)(wsb + oMsg);
  u16*   alpha16 = (u16*)(wsb + oAlpha);
  u16*   nacc    = (u16*)(wsb + oNacc);
  u16*   feat_e  = (u16*)(wsb + oFeatE);
  u16*   xnf     = (u16*)(wsb + oXnf);
  u16*   BTf_bp  = (u16*)(wsb + oBTbp);
  u16*   BTf_fo  = (u16*)(wsb + oBTfo);
  int*   deg2    = (int*)(wsb + oDeg2);
  int*   npairs  = deg2 + N2;               // zeroed together with deg2
  int*   start2  = (int*)(wsb + oStart2);
  int*   cursor2 = (int*)(wsb + oCur2);
  int*   bucket2 = (int*)(wsb + oBuk2);
  int*   bsum    = (int*)(wsb + oBsum);
  int2*  pairs   = (int2*)(wsb + oPairs);
  u16*   corrbuf = (u16*)(wsb + oCorrB);
  // hbuf overlays msg (msg dead after the final k_nodesum)
  float* hbuf    = (float*)(wsb + oMsg);                      // 51.2 MB

  const int egrid256 = (E+255)/256;
  const int kgrid256 = (K+255)/256;
  const int egrid    = (E+63)/64;
  const int nb       = (N2+255)/256;   // scan blocks (<=1024)

  k_prep_B<<<320, 256, 0, stream>>>(W_i, W_h, W_o, BTf_bp, BTf_fo);
  k_feat_e<<<(E*64+255)/256, 256, 0, stream>>>(x_nodes, x_edges, edge_src, feat_e, E);
  k_xnf<<<((long long)N*64+255)/256, 256, 0, stream>>>(x_nodes, xnf, N);

  // concatenated histograms: deg2=[deg_tgt | deg_dst] (+ npairs slot zeroed)
  k_zero_int<<<(N2+1+255)/256, 256, 0, stream>>>(deg2, N2+1);
  k_hist<<<kgrid256, 256, 0, stream>>>(tgt, deg2, K);
  k_hist<<<egrid256, 256, 0, stream>>>(edge_dst, deg2 + N, E);

  // one parallel scan over 2N -> start2/cursor2 (positions into concatenated bucket2)
  k_scan_p1<<<nb, 256, 0, stream>>>(deg2, N2, bsum);
  k_scan_p2<<<1, 1024, 0, stream>>>(bsum, nb, start2 + N2);   // start2[2N] = K+E
  k_scan_p3<<<nb, 256, 0, stream>>>(deg2, bsum, N2, start2, cursor2);

  k_fill<<<kgrid256, 256, 0, stream>>>(tgt, teid, cursor2, bucket2, K);
  k_fill<<<egrid256, 256, 0, stream>>>(edge_dst, (const int*)0, cursor2 + N, bucket2, E);

  k_alpha_gather<<<(N+3)/4, 256, 0, stream>>>(tree_m, start2, bucket2, alpha16, N);
  k_pairs<<<egrid256, 256, 0, stream>>>(edge_src, edge_dst, start2 + N, bucket2,
                                        npairs, pairs, E);

  // iter0: msg = relu(feat_e @ Wi)
  k_mpnn<<<egrid, 256, 0, stream>>>(feat_e, (const u16*)0, (const int*)0,
                                    BTf_bp, (const float*)0, msg, (float*)0, E, 0);
  // BP iters: nodeacc = segsum_dst(msg)+alpha; snapshot pair rows; in-place GEMM; fixup
  for (int it=0; it<3; ++it){
    k_nodesum<<<(N+3)/4, 256, 0, stream>>>(msg, alpha16, start2 + N, bucket2, nacc, N);
    k_snapshot<<<32, 256, 0, stream>>>(msg, pairs, npairs, corrbuf);
    k_mpnn<<<egrid, 256, 0, stream>>>(feat_e, nacc, edge_src,
                                      BTf_bp, (const float*)0, msg, (float*)0, E, 1);
    k_fixup<<<64, 256, 0, stream>>>(x_nodes, x_edges, edge_src, nacc, corrbuf,
                                    pairs, npairs, W_i, W_h, msg);
  }
  // output layer: m + node_alpha == nodeacc(final msg)
  k_nodesum<<<(N+3)/4, 256, 0, stream>>>(msg, alpha16, start2 + N, bucket2, nacc, N);
  k_mpnn<<<(N+63)/64, 256, 0, stream>>>(xnf, nacc, (const int*)0,
                                        BTf_fo, b_o, (u16*)0, hbuf, N, 2);
  k_graph_mean<<<(G+3)/4, 256, 0, stream>>>(hbuf, gid, N, G, (float*)d_out);
}

// Round 4
// 655.563 us; speedup vs baseline: 2.5755x; 1.5596x over previous
//
#include <hip/hip_runtime.h>
#include <stdint.h>

typedef unsigned short u16;
typedef __attribute__((ext_vector_type(8))) short bf16x8;
typedef __attribute__((ext_vector_type(4))) float f32x4;

#define HD 256
#define AST 328       // A_lds row stride in u16 (656 B = 41*16: 16B-aligned, bank-rotating)
#define CORR_CAP 8192 // backtracking-pair capacity (expected ~16 for this graph)

static __device__ __forceinline__ float b2f(u16 x){
  union{float f; unsigned u;} v; v.u = ((unsigned)x)<<16; return v.f;
}
static __device__ __forceinline__ u16 f2b(float f){
  union{float f; unsigned u;} v; v.f = f;
  unsigned r = v.u + 0x7fffu + ((v.u>>16)&1u);
  return (u16)(r>>16);
}
static __device__ __forceinline__ void acc4(float* a, uint2 v){
  a[0] += b2f((u16)v.x); a[1] += b2f((u16)(v.x>>16));
  a[2] += b2f((u16)v.y); a[3] += b2f((u16)(v.y>>16));
}

// ---------------- zero int buffer ----------------
__global__ void k_zero_int(int* __restrict__ p, int n){
  int i = blockIdx.x*256 + threadIdx.x;
  if (i < n) p[i] = 0;
}

// ---------------- histogram ----------------
__global__ void k_hist(const int* __restrict__ key, int* __restrict__ deg, int n){
  int i = blockIdx.x*256 + threadIdx.x;
  if (i < n) atomicAdd(&deg[key[i]], 1);
}

// ---------------- 3-phase parallel exclusive scan ----------------
__global__ void k_scan_p1(const int* __restrict__ deg, int n, int* __restrict__ bsum){
  int i = blockIdx.x*256 + threadIdx.x;
  int v = (i < n) ? deg[i] : 0;
  #pragma unroll
  for (int o=32; o>0; o>>=1) v += __shfl_down(v, o);
  __shared__ int w[4];
  if ((threadIdx.x&63)==0) w[threadIdx.x>>6] = v;
  __syncthreads();
  if (threadIdx.x==0) bsum[blockIdx.x] = w[0]+w[1]+w[2]+w[3];
}
__global__ __launch_bounds__(1024) void k_scan_p2(int* __restrict__ bsum, int nb,
                                                  int* __restrict__ total_dst){
  __shared__ int sm[1024];
  int t = threadIdx.x;
  int v = (t < nb) ? bsum[t] : 0;
  sm[t] = v; __syncthreads();
  for (int o=1; o<1024; o<<=1){
    int u = (t>=o) ? sm[t-o] : 0;
    __syncthreads();
    sm[t] += u;
    __syncthreads();
  }
  if (t < nb) bsum[t] = sm[t] - v;
  if (t == 1023 && total_dst) *total_dst = sm[1023];
}
__global__ void k_scan_p3(const int* __restrict__ deg, const int* __restrict__ bsum, int n,
                          int* __restrict__ start, int* __restrict__ cursor){
  int t = threadIdx.x;
  int i = blockIdx.x*256 + t;
  int v = (i < n) ? deg[i] : 0;
  __shared__ int sm[256];
  sm[t] = v; __syncthreads();
  for (int o=1; o<256; o<<=1){
    int u = (t>=o) ? sm[t-o] : 0;
    __syncthreads();
    sm[t] += u;
    __syncthreads();
  }
  int ex = sm[t] - v + bsum[blockIdx.x];
  if (i < n){ start[i] = ex; cursor[i] = ex; }
}

// ---------------- fill buckets ----------------
__global__ void k_fill(const int* __restrict__ key, const int* __restrict__ val,
                       int* __restrict__ cursor, int* __restrict__ bucket, int n){
  int i = blockIdx.x*256 + threadIdx.x;
  if (i >= n) return;
  int pos = atomicAdd(&cursor[key[i]], 1);
  bucket[pos] = val ? val[i] : i;
}

// ---------------- permuted edge arrays (new label = dst-sorted rank) ----------------
__global__ void k_permarr(const int* __restrict__ perm, const int* __restrict__ esrc,
                          const int* __restrict__ edst, int* __restrict__ esrc_p,
                          int* __restrict__ edst_p, int E){
  int e = blockIdx.x*256 + threadIdx.x;
  if (e >= E) return;
  int o = perm[e];
  esrc_p[e] = esrc[o];
  edst_p[e] = edst[o];
}

// feat[e_new][64] = [ xn[src] (35) | xe[old] (5) | 0 pad ]  (bf16)
__global__ void k_feat_e(const float* __restrict__ xn, const float* __restrict__ xe,
                         const int* __restrict__ perm, const int* __restrict__ esrc_p,
                         u16* __restrict__ feat, int E){
  int g = blockIdx.x*256 + threadIdx.x;
  int e = g >> 6, c = g & 63;
  if (e >= E) return;
  float v = 0.f;
  if (c < 35) v = xn[(size_t)esrc_p[e]*35 + c];
  else if (c < 40) v = xe[(size_t)perm[e]*5 + (c-35)];
  feat[g] = f2b(v);
}
// xnf[v][64] = [ xn[v] (35) | 0 pad ]  (bf16)
__global__ void k_xnf(const float* __restrict__ xn, u16* __restrict__ xnf, int N){
  int g = blockIdx.x*256 + threadIdx.x;
  int v2 = g >> 6, c = g & 63;
  if (v2 >= N) return;
  float v = (c < 35) ? xn[(size_t)v2*35 + c] : 0.f;
  xnf[g] = f2b(v);
}

// ---------------- alpha16[v] = bf16( sum_{j} tree_m[bucket[j]] ) ----------------
__global__ void k_alpha_gather(const float* __restrict__ tree_m, const int* __restrict__ start,
                               const int* __restrict__ bucket, u16* __restrict__ alpha16, int N){
  int v = (int)(((long long)blockIdx.x*blockDim.x + threadIdx.x)>>6);
  int l = threadIdx.x & 63;
  if (v >= N) return;
  int s = start[v], e2 = start[v+1];
  float a0=0.f,a1=0.f,a2=0.f,a3=0.f;
  for (int j=s;j<e2;j++){
    float4 tv = *(const float4*)(tree_m + (size_t)bucket[j]*HD + l*4);
    a0 += tv.x; a1 += tv.y; a2 += tv.z; a3 += tv.w;
  }
  ushort4 o; o.x=f2b(a0); o.y=f2b(a1); o.z=f2b(a2); o.w=f2b(a3);
  *(ushort4*)(alpha16 + (size_t)v*HD + l*4) = o;
}

// ---------------- nodeacc[v] = bf16( alpha[v] + sum of msg segment ) — STREAMING ----------------
// edges relabeled dst-sorted: node v's in-edges are msg rows [start_d[v], start_d[v+1])
__global__ void k_nodesum(const u16* __restrict__ msg, const u16* __restrict__ alpha16,
                          const int* __restrict__ start_d, u16* __restrict__ nodeacc, int N){
  int v = (int)(((long long)blockIdx.x*blockDim.x + threadIdx.x)>>6);
  int l = threadIdx.x & 63;
  if (v >= N) return;
  int s = start_d[v], e2 = start_d[v+1];
  float a[4];
  { uint2 av = *(const uint2*)(alpha16 + (size_t)v*HD + l*4);
    a[0]=b2f((u16)av.x); a[1]=b2f((u16)(av.x>>16));
    a[2]=b2f((u16)av.y); a[3]=b2f((u16)(av.y>>16)); }
  const u16* ml = msg + (size_t)s*HD + l*4;
  int cnt = e2 - s;
  int j = 0;
  for (; j+2 <= cnt; j+=2){
    uint2 v0 = *(const uint2*)(ml);
    uint2 v1 = *(const uint2*)(ml + HD);
    ml += 2*HD;
    acc4(a, v0); acc4(a, v1);
  }
  for (; j < cnt; j++){
    uint2 v0 = *(const uint2*)(ml); ml += HD;
    acc4(a, v0);
  }
  ushort4 o; o.x=f2b(a[0]); o.y=f2b(a[1]); o.z=f2b(a[2]); o.w=f2b(a[3]);
  *(ushort4*)(nodeacc + (size_t)v*HD + l*4) = o;
}

// ---------------- backtracking pair list (new labels; segment = contiguous range) ----------------
__global__ void k_pairs(const int* __restrict__ esrc_p, const int* __restrict__ edst_p,
                        const int* __restrict__ start_d,
                        int* __restrict__ npairs, int2* __restrict__ pairs, int E){
  int e = blockIdx.x*256 + threadIdx.x;
  if (e >= E) return;
  int u = esrc_p[e], v = edst_p[e];
  int s = start_d[u], t = start_d[u+1];
  for (int ep=s; ep<t; ep++){
    if (esrc_p[ep] == v){
      int pos = atomicAdd(npairs, 1);
      if (pos < CORR_CAP) pairs[pos] = (int2){e, ep};
    }
  }
}

// snapshot old msg rows of pair partners before in-place msg overwrite
__global__ void k_snapshot(const u16* __restrict__ msg, const int2* __restrict__ pairs,
                           const int* __restrict__ npairs_p, u16* __restrict__ corrbuf){
  int np = *npairs_p; if (np > CORR_CAP) np = CORR_CAP;
  int wid = (blockIdx.x*256 + threadIdx.x) >> 6;
  int l = threadIdx.x & 63;
  int nw = gridDim.x * 4;
  for (int p = wid; p < np; p += nw){
    int ep = pairs[p].y;
    *(uint2*)(corrbuf + (size_t)p*HD + l*4) =
        *(const uint2*)(msg + (size_t)ep*HD + l*4);
  }
}

// exact fp32 recompute of the (rare) backtracking-affected msg rows, overwrite after GEMM
__global__ __launch_bounds__(256) void k_fixup(
    const float* __restrict__ xn, const float* __restrict__ xe,
    const int* __restrict__ perm, const int* __restrict__ esrc_p,
    const u16* __restrict__ nacc, const u16* __restrict__ corrbuf,
    const int2* __restrict__ pairs, const int* __restrict__ npairs_p,
    const float* __restrict__ Wi, const float* __restrict__ Wh, u16* __restrict__ msg){
  int np = *npairs_p; if (np > CORR_CAP) np = CORR_CAP;
  int t = threadIdx.x;
  __shared__ float cs[256];
  for (int p = blockIdx.x; p < np; p += gridDim.x){
    int e = pairs[p].x;
    bool first = true;
    for (int q=0;q<p;q++) if (pairs[q].x == e){ first = false; break; }
    if (!first) continue;                 // block-uniform branch
    int u = esrc_p[e];
    float c = 0.f;
    for (int q=p;q<np;q++) if (pairs[q].x == e) c += b2f(corrbuf[(size_t)q*HD + t]);
    cs[t] = c; __syncthreads();
    float acc = 0.f;
    for (int k=0;k<35;k++) acc += xn[(size_t)u*35 + k] * Wi[k*HD + t];
    int oe = perm[e];
    for (int k=0;k<5;k++)  acc += xe[(size_t)oe*5 + k] * Wi[(35+k)*HD + t];
    for (int k=0;k<HD;k++) acc += (b2f(nacc[(size_t)u*HD + k]) - cs[k]) * Wh[k*HD + t];
    msg[(size_t)e*HD + t] = f2b(acc > 0.f ? acc : 0.f);
    __syncthreads();
  }
}

// ---------------- frag-major B prep ----------------
__global__ void k_prep_B(const float* __restrict__ Wi, const float* __restrict__ Wh,
                         const float* __restrict__ Wo,
                         u16* __restrict__ BTf_bp, u16* __restrict__ BTf_fo){
  int g = blockIdx.x*256 + threadIdx.x;   // 81920 total
  if (g >= 81920) return;
  int i = g & 7;
  int l = (g>>3) & 63;
  int t = g >> 9;                // 0..159
  int nj = t & 15, ks = t >> 4;  // ks 0..9
  int n = nj*16 + (l & 15);
  int k = ks*32 + (l>>4)*8 + i;
  float bp = 0.f, fo = 0.f;
  if (k < 40) bp = Wi[k*HD + n];
  else if (k >= 64) bp = Wh[(k-64)*HD + n];
  if (k < 35) fo = Wo[k*HD + n];
  else if (k >= 64) fo = Wo[(k-29)*HD + n];
  BTf_bp[g] = f2b(bp);
  BTf_fo[g] = f2b(fo);
}

// ---------------- fused MPNN GEMM: B in registers, persistent row-block loop ----------------
// 512 threads = 8 waves; wave w owns output cols [w*32, w*32+32) (nj = w*2, w*2+1).
// Per row-block (16 rows): A staged in LDS [16][AST] (feat cols 0..63 | nacc cols 64..319).
// T14 split: next row-block's global loads issue before compute, ds_write after barrier.
// mode 0: ksteps 2 (feat only);  mode 1: ksteps 10, nacc row = esrc[row];  mode 2: nacc row = row, +bias, fp32 out.
__global__ __launch_bounds__(512, 4) void k_mpnn(
    const u16* __restrict__ featA, const u16* __restrict__ nacc,
    const int* __restrict__ esrc,
    const u16* __restrict__ BTf, const float* __restrict__ bias,
    u16* __restrict__ out16, float* __restrict__ out32, int M, int mode)
{
  __shared__ u16 A_lds[16][AST];   // 10,496 B
  const int tid = threadIdx.x;
  const int w = tid>>6, l = tid&63;
  const int lr = l&15, lq = l>>4;
  const int nks = (mode==0) ? 2 : 10;
  const int nrb = (M+15)>>4;
  const int gstep = gridDim.x;

  // ---- per-wave B registers (loaded once)
  bf16x8 Breg0[10], Breg1[10];
  #pragma unroll
  for (int ks=0; ks<10; ks++){
    if (ks < nks){
      Breg0[ks] = *(const bf16x8*)(BTf + (size_t)((ks*16 + w*2    )*512) + l*8);
      Breg1[ks] = *(const bf16x8*)(BTf + (size_t)((ks*16 + w*2 + 1)*512) + l*8);
    }
  }

  const int c0 = (w*2)*16 + lr, c1 = (w*2+1)*16 + lr;
  float b0 = 0.f, b1 = 0.f;
  if (mode == 2){ b0 = bias[c0]; b1 = bias[c1]; }

  uint2 fA={0,0}, fB={0,0}, nA={0,0}, nB={0,0};
  int rb = blockIdx.x;

  // ---- prologue: load + stage first row-block
  if (rb < nrb){
    int rr0 = rb*16 + w*2;
    int r0 = min(rr0, M-1), r1 = min(rr0+1, M-1);
    if (l < 16){
      fA = *(const uint2*)(featA + (size_t)r0*64 + l*4);
      fB = *(const uint2*)(featA + (size_t)r1*64 + l*4);
    }
    if (mode != 0){
      int s0 = esrc ? esrc[r0] : r0;
      int s1 = esrc ? esrc[r1] : r1;
      nA = *(const uint2*)(nacc + (size_t)s0*HD + l*4);
      nB = *(const uint2*)(nacc + (size_t)s1*HD + l*4);
    }
    if (l < 16){
      *(uint2*)&A_lds[w*2  ][l*4] = fA;
      *(uint2*)&A_lds[w*2+1][l*4] = fB;
    }
    if (mode != 0){
      *(uint2*)&A_lds[w*2  ][64 + l*4] = nA;
      *(uint2*)&A_lds[w*2+1][64 + l*4] = nB;
    }
  }
  __syncthreads();

  for (; rb < nrb; rb += gstep){
    int rbn = rb + gstep;
    // ---- issue next row-block's global loads (latency hides under compute)
    if (rbn < nrb){
      int rr0 = rbn*16 + w*2;
      int r0 = min(rr0, M-1), r1 = min(rr0+1, M-1);
      if (l < 16){
        fA = *(const uint2*)(featA + (size_t)r0*64 + l*4);
        fB = *(const uint2*)(featA + (size_t)r1*64 + l*4);
      }
      if (mode != 0){
        int s0 = esrc ? esrc[r0] : r0;
        int s1 = esrc ? esrc[r1] : r1;
        nA = *(const uint2*)(nacc + (size_t)s0*HD + l*4);
        nB = *(const uint2*)(nacc + (size_t)s1*HD + l*4);
      }
    }

    // ---- compute current row-block from LDS
    f32x4 acc0 = (f32x4){0.f,0.f,0.f,0.f};
    f32x4 acc1 = (f32x4){0.f,0.f,0.f,0.f};
    const u16* Ar = &A_lds[lr][0];
    #pragma unroll
    for (int ks=0; ks<10; ks++){
      if (ks < nks){
        bf16x8 a = *(const bf16x8*)(Ar + ks*32 + lq*8);
        acc0 = __builtin_amdgcn_mfma_f32_16x16x32_bf16(a, Breg0[ks], acc0, 0,0,0);
        acc1 = __builtin_amdgcn_mfma_f32_16x16x32_bf16(a, Breg1[ks], acc1, 0,0,0);
      }
    }

    // ---- epilogue: C/D layout col=lr, row=lq*4+reg
    int m0 = rb*16;
    if (mode == 2){
      #pragma unroll
      for (int reg=0; reg<4; reg++){
        int gm = m0 + lq*4 + reg;
        if (gm < M){
          float v0 = acc0[reg] + b0, v1 = acc1[reg] + b1;
          out32[(size_t)gm*HD + c0] = v0 > 0.f ? v0 : 0.f;
          out32[(size_t)gm*HD + c1] = v1 > 0.f ? v1 : 0.f;
        }
      }
    } else {
      #pragma unroll
      for (int reg=0; reg<4; reg++){
        int gm = m0 + lq*4 + reg;
        if (gm < M){
          float v0 = acc0[reg], v1 = acc1[reg];
          out16[(size_t)gm*HD + c0] = f2b(v0 > 0.f ? v0 : 0.f);
          out16[(size_t)gm*HD + c1] = f2b(v1 > 0.f ? v1 : 0.f);
        }
      }
    }

    __syncthreads();
    // ---- write next row-block's staged data into LDS
    if (rbn < nrb){
      if (l < 16){
        *(uint2*)&A_lds[w*2  ][l*4] = fA;
        *(uint2*)&A_lds[w*2+1][l*4] = fB;
      }
      if (mode != 0){
        *(uint2*)&A_lds[w*2  ][64 + l*4] = nA;
        *(uint2*)&A_lds[w*2+1][64 + l*4] = nB;
      }
    }
    __syncthreads();
  }
}

// ---------------- graph mean (graph_ids sorted), fp32 in/out ----------------
__global__ void k_graph_mean(const float* __restrict__ h, const int* __restrict__ gid,
                             int N, int G, float* __restrict__ out){
  int g = (int)(((long long)blockIdx.x*blockDim.x + threadIdx.x)>>6);
  int l = threadIdx.x & 63;
  if (g >= G) return;
  int lo=0, hi=N;
  while (lo<hi){ int mid=(lo+hi)>>1; if (gid[mid] < g) lo=mid+1; else hi=mid; }
  int b = lo;
  hi = N;
  while (lo<hi){ int mid=(lo+hi)>>1; if (gid[mid] < g+1) lo=mid+1; else hi=mid; }
  int e2 = lo;
  float a0=0.f,a1=0.f,a2=0.f,a3=0.f;
  for (int v=b; v<e2; v++){
    float4 hv = *(const float4*)(h + (size_t)v*HD + l*4);
    a0 += hv.x; a1 += hv.y; a2 += hv.z; a3 += hv.w;
  }
  int cnt = e2 - b; if (cnt < 1) cnt = 1;
  float inv = 1.0f/(float)cnt;
  float4 o; o.x=a0*inv; o.y=a1*inv; o.z=a2*inv; o.w=a3*inv;
  *(float4*)(out + (size_t)g*HD + l*4) = o;
}

extern "C" void kernel_launch(void* const* d_in, const int* in_sizes, int n_in,
                              void* d_out, int out_size, void* d_ws, size_t ws_size,
                              hipStream_t stream){
  const float* x_nodes = (const float*)d_in[0];
  const float* x_edges = (const float*)d_in[1];
  const float* tree_m  = (const float*)d_in[2];
  const float* W_i     = (const float*)d_in[3];
  const float* W_h     = (const float*)d_in[4];
  const float* W_o     = (const float*)d_in[5];
  const float* b_o     = (const float*)d_in[6];
  const int* edge_src = (const int*)d_in[7];
  const int* edge_dst = (const int*)d_in[8];
  const int* tgt      = (const int*)d_in[11];
  const int* teid     = (const int*)d_in[12];
  const int* gid      = (const int*)d_in[13];

  const int N = in_sizes[0]/35;
  const int E = in_sizes[1]/5;
  const int K = in_sizes[11];
  const int G = out_size/HD;

  // ---- workspace layout (~195 MB footprint) ----
  char* wsb = (char*)d_ws;
  auto align256 = [](size_t x){ return (x + 255) & ~(size_t)255; };
  size_t oMsg    = 0;
  size_t oAlpha  = oMsg    + align256((size_t)E*HD*2);        // 102.4 MB
  size_t oNacc   = oAlpha  + align256((size_t)N*HD*2);        // 25.6 MB
  size_t oFeatE  = oNacc   + align256((size_t)N*HD*2);        // 25.6 MB
  size_t oXnf    = oFeatE  + align256((size_t)E*64*2);        // 25.6 MB
  size_t oBTbp   = oXnf    + align256((size_t)N*64*2);        // 6.4 MB
  size_t oBTfo   = oBTbp   + align256((size_t)81920*2);       // 160 KB
  size_t oDegD   = oBTfo   + align256((size_t)81920*2);       // N+1 ints ([N] = npairs)
  size_t oStartD = oDegD   + align256((size_t)(N+1)*4);       // N+1 ints
  size_t oCurD   = oStartD + align256((size_t)(N+1)*4);       // N ints
  size_t oPerm   = oCurD   + align256((size_t)N*4);           // E ints
  size_t oEsrcP  = oPerm   + align256((size_t)E*4);           // E ints
  size_t oEdstP  = oEsrcP  + align256((size_t)E*4);           // E ints
  size_t oDegT   = oEdstP  + align256((size_t)E*4);           // N ints
  size_t oStartT = oDegT   + align256((size_t)N*4);           // N+1 ints
  size_t oCurT   = oStartT + align256((size_t)(N+1)*4);       // N ints
  size_t oBukT   = oCurT   + align256((size_t)N*4);           // K ints
  size_t oBsum   = oBukT   + align256((size_t)K*4);           // 1024 ints
  size_t oPairs  = oBsum   + align256((size_t)1024*4);        // CORR_CAP int2
  size_t oCorrB  = oPairs  + align256((size_t)CORR_CAP*8);    // 4 MB

  u16*   msg     = (u16*)(wsb + oMsg);
  u16*   alpha16 = (u16*)(wsb + oAlpha);
  u16*   nacc    = (u16*)(wsb + oNacc);
  u16*   feat_e  = (u16*)(wsb + oFeatE);
  u16*   xnf     = (u16*)(wsb + oXnf);
  u16*   BTf_bp  = (u16*)(wsb + oBTbp);
  u16*   BTf_fo  = (u16*)(wsb + oBTfo);
  int*   deg_d   = (int*)(wsb + oDegD);
  int*   npairs  = deg_d + N;               // zeroed together with deg_d
  int*   start_d = (int*)(wsb + oStartD);
  int*   cur_d   = (int*)(wsb + oCurD);
  int*   perm    = (int*)(wsb + oPerm);
  int*   esrc_p  = (int*)(wsb + oEsrcP);
  int*   edst_p  = (int*)(wsb + oEdstP);
  int*   deg_t   = (int*)(wsb + oDegT);
  int*   start_t = (int*)(wsb + oStartT);
  int*   cur_t   = (int*)(wsb + oCurT);
  int*   buk_t   = (int*)(wsb + oBukT);
  int*   bsum    = (int*)(wsb + oBsum);
  int2*  pairs   = (int2*)(wsb + oPairs);
  u16*   corrbuf = (u16*)(wsb + oCorrB);
  // hbuf overlays msg (msg dead after the final k_nodesum)
  float* hbuf    = (float*)(wsb + oMsg);                      // 51.2 MB

  const int egrid256 = (E+255)/256;
  const int kgrid256 = (K+255)/256;
  const int ngrid256 = (N+255)/256;
  const int nbN      = (N+255)/256;    // scan blocks over N (<=1024)

  k_prep_B<<<320, 256, 0, stream>>>(W_i, W_h, W_o, BTf_bp, BTf_fo);

  // ---- dst-CSR -> edge permutation (new label = dst-sorted rank)
  k_zero_int<<<(N+1+255)/256, 256, 0, stream>>>(deg_d, N+1);
  k_hist<<<egrid256, 256, 0, stream>>>(edge_dst, deg_d, E);
  k_scan_p1<<<nbN, 256, 0, stream>>>(deg_d, N, bsum);
  k_scan_p2<<<1, 1024, 0, stream>>>(bsum, nbN, start_d + N);  // start_d[N] = E
  k_scan_p3<<<nbN, 256, 0, stream>>>(deg_d, bsum, N, start_d, cur_d);
  k_fill<<<egrid256, 256, 0, stream>>>(edge_dst, (const int*)0, cur_d, perm, E);
  k_permarr<<<egrid256, 256, 0, stream>>>(perm, edge_src, edge_dst, esrc_p, edst_p, E);
  k_feat_e<<<((size_t)E*64+255)/256, 256, 0, stream>>>(x_nodes, x_edges, perm, esrc_p, feat_e, E);
  k_xnf<<<((size_t)N*64+255)/256, 256, 0, stream>>>(x_nodes, xnf, N);

  // ---- tgt-CSR + alpha gather
  k_zero_int<<<ngrid256, 256, 0, stream>>>(deg_t, N);
  k_hist<<<kgrid256, 256, 0, stream>>>(tgt, deg_t, K);
  k_scan_p1<<<nbN, 256, 0, stream>>>(deg_t, N, bsum);
  k_scan_p2<<<1, 1024, 0, stream>>>(bsum, nbN, start_t + N);  // start_t[N] = K
  k_scan_p3<<<nbN, 256, 0, stream>>>(deg_t, bsum, N, start_t, cur_t);
  k_fill<<<kgrid256, 256, 0, stream>>>(tgt, teid, cur_t, buk_t, K);
  k_alpha_gather<<<(N+3)/4, 256, 0, stream>>>(tree_m, start_t, buk_t, alpha16, N);

  k_pairs<<<egrid256, 256, 0, stream>>>(esrc_p, edst_p, start_d, npairs, pairs, E);

  // ---- iter0: msg = relu(feat_e @ Wi)   (rows in new edge labels)
  k_mpnn<<<512, 512, 0, stream>>>(feat_e, (const u16*)0, (const int*)0,
                                  BTf_bp, (const float*)0, msg, (float*)0, E, 0);
  // ---- BP iters: nodeacc = streaming segsum + alpha; snapshot; in-place GEMM; fixup
  for (int it=0; it<3; ++it){
    k_nodesum<<<(N+3)/4, 256, 0, stream>>>(msg, alpha16, start_d, nacc, N);
    k_snapshot<<<32, 256, 0, stream>>>(msg, pairs, npairs, corrbuf);
    k_mpnn<<<512, 512, 0, stream>>>(feat_e, nacc, esrc_p,
                                    BTf_bp, (const float*)0, msg, (float*)0, E, 1);
    k_fixup<<<64, 256, 0, stream>>>(x_nodes, x_edges, perm, esrc_p, nacc, corrbuf,
                                    pairs, npairs, W_i, W_h, msg);
  }
  // ---- output layer: m + node_alpha == nodeacc(final msg)
  k_nodesum<<<(N+3)/4, 256, 0, stream>>>(msg, alpha16, start_d, nacc, N);
  k_mpnn<<<512, 512, 0, stream>>>(xnf, nacc, (const int*)0,
                                  BTf_fo, b_o, (u16*)0, hbuf, N, 2);
  k_graph_mean<<<(G+3)/4, 256, 0, stream>>>(hbuf, gid, N, G, (float*)d_out);
}

// Round 5
// 639.950 us; speedup vs baseline: 2.6383x; 1.0244x over previous
//
#include <hip/hip_runtime.h>
#include <stdint.h>

typedef unsigned short u16;
typedef __attribute__((ext_vector_type(8))) short bf16x8;
typedef __attribute__((ext_vector_type(4))) float f32x4;

#define HD 256
#define AST 264       // A_lds row stride in u16 (528 B: 16B-aligned, 2-way-max frag reads)
#define CORR_CAP 2048 // backtracking-pair capacity (expected ~16 for this graph)

static __device__ __forceinline__ float b2f(u16 x){
  union{float f; unsigned u;} v; v.u = ((unsigned)x)<<16; return v.f;
}
static __device__ __forceinline__ u16 f2b(float f){
  union{float f; unsigned u;} v; v.f = f;
  unsigned r = v.u + 0x7fffu + ((v.u>>16)&1u);
  return (u16)(r>>16);
}
static __device__ __forceinline__ void acc4(float* a, uint2 v){
  a[0] += b2f((u16)v.x); a[1] += b2f((u16)(v.x>>16));
  a[2] += b2f((u16)v.y); a[3] += b2f((u16)(v.y>>16));
}

// ---------------- zero int buffer ----------------
__global__ void k_zero_int(int* __restrict__ p, int n){
  int i = blockIdx.x*256 + threadIdx.x;
  if (i < n) p[i] = 0;
}

// ---------------- histogram ----------------
__global__ void k_hist(const int* __restrict__ key, int* __restrict__ deg, int n){
  int i = blockIdx.x*256 + threadIdx.x;
  if (i < n) atomicAdd(&deg[key[i]], 1);
}

// ---------------- 3-phase parallel exclusive scan ----------------
__global__ void k_scan_p1(const int* __restrict__ deg, int n, int* __restrict__ bsum){
  int i = blockIdx.x*256 + threadIdx.x;
  int v = (i < n) ? deg[i] : 0;
  #pragma unroll
  for (int o=32; o>0; o>>=1) v += __shfl_down(v, o);
  __shared__ int w[4];
  if ((threadIdx.x&63)==0) w[threadIdx.x>>6] = v;
  __syncthreads();
  if (threadIdx.x==0) bsum[blockIdx.x] = w[0]+w[1]+w[2]+w[3];
}
__global__ __launch_bounds__(1024) void k_scan_p2(int* __restrict__ bsum, int nb,
                                                  int* __restrict__ total_dst){
  __shared__ int sm[1024];
  int t = threadIdx.x;
  int v = (t < nb) ? bsum[t] : 0;
  sm[t] = v; __syncthreads();
  for (int o=1; o<1024; o<<=1){
    int u = (t>=o) ? sm[t-o] : 0;
    __syncthreads();
    sm[t] += u;
    __syncthreads();
  }
  if (t < nb) bsum[t] = sm[t] - v;
  if (t == 1023 && total_dst) *total_dst = sm[1023];
}
__global__ void k_scan_p3(const int* __restrict__ deg, const int* __restrict__ bsum, int n,
                          int* __restrict__ start, int* __restrict__ cursor){
  int t = threadIdx.x;
  int i = blockIdx.x*256 + t;
  int v = (i < n) ? deg[i] : 0;
  __shared__ int sm[256];
  sm[t] = v; __syncthreads();
  for (int o=1; o<256; o<<=1){
    int u = (t>=o) ? sm[t-o] : 0;
    __syncthreads();
    sm[t] += u;
    __syncthreads();
  }
  int ex = sm[t] - v + bsum[blockIdx.x];
  if (i < n){ start[i] = ex; cursor[i] = ex; }
}

// ---------------- fill buckets ----------------
__global__ void k_fill(const int* __restrict__ key, const int* __restrict__ val,
                       int* __restrict__ cursor, int* __restrict__ bucket, int n){
  int i = blockIdx.x*256 + threadIdx.x;
  if (i >= n) return;
  int pos = atomicAdd(&cursor[key[i]], 1);
  bucket[pos] = val ? val[i] : i;
}

// ---------------- permuted edge arrays (new label = dst-sorted rank) ----------------
__global__ void k_permarr(const int* __restrict__ perm, const int* __restrict__ esrc,
                          const int* __restrict__ edst, int* __restrict__ esrc_p,
                          int* __restrict__ edst_p, int E){
  int e = blockIdx.x*256 + threadIdx.x;
  if (e >= E) return;
  int o = perm[e];
  esrc_p[e] = esrc[o];
  edst_p[e] = edst[o];
}

// xep[e][5] = xe[perm[e]][5]
__global__ void k_xep(const float* __restrict__ xe, const int* __restrict__ perm,
                      float* __restrict__ xep, int E){
  int e = blockIdx.x*256 + threadIdx.x;
  if (e >= E) return;
  int o = perm[e];
  #pragma unroll
  for (int k=0;k<5;k++) xep[(size_t)e*5+k] = xe[(size_t)o*5+k];
}

// xnf[v][64] = [ xn[v] (35) | 0 pad ]  (bf16)
__global__ void k_xnf(const float* __restrict__ xn, u16* __restrict__ xnf, int N){
  int g = blockIdx.x*256 + threadIdx.x;
  int v2 = g >> 6, c = g & 63;
  if (v2 >= N) return;
  float v = (c < 35) ? xn[(size_t)v2*35 + c] : 0.f;
  xnf[g] = f2b(v);
}

// ---------------- alpha16[v] = bf16( sum_{j} tree_m[bucket[j]] ) ----------------
__global__ void k_alpha_gather(const float* __restrict__ tree_m, const int* __restrict__ start,
                               const int* __restrict__ bucket, u16* __restrict__ alpha16, int N){
  int v = (int)(((long long)blockIdx.x*blockDim.x + threadIdx.x)>>6);
  int l = threadIdx.x & 63;
  if (v >= N) return;
  int s = start[v], e2 = start[v+1];
  float a0=0.f,a1=0.f,a2=0.f,a3=0.f;
  for (int j=s;j<e2;j++){
    float4 tv = *(const float4*)(tree_m + (size_t)bucket[j]*HD + l*4);
    a0 += tv.x; a1 += tv.y; a2 += tv.z; a3 += tv.w;
  }
  ushort4 o; o.x=f2b(a0); o.y=f2b(a1); o.z=f2b(a2); o.w=f2b(a3);
  *(ushort4*)(alpha16 + (size_t)v*HD + l*4) = o;
}

// ---------------- generic frag-major B-table builder ----------------
// out[(ks*16+nj)*512 + l*8 + i] = W[(k0 + k)*256 + nj*16+(l&15)], k = ks*32+(l>>4)*8+i, 0 if k>=kmax
__global__ void k_prep_frag(const float* __restrict__ W, int k0, int kmax, int nks,
                            u16* __restrict__ out){
  int g = blockIdx.x*256 + threadIdx.x;
  if (g >= nks*16*512) return;
  int i = g & 7, l = (g>>3)&63, t = g>>9;
  int nj = t & 15, ks = t >> 4;
  int n = nj*16 + (l&15);
  int k = ks*32 + (l>>4)*8 + i;
  float v = (k < kmax) ? W[(size_t)(k0+k)*HD + n] : 0.f;
  out[g] = f2b(v);
}

// ---------------- P/R GEMM: out = featA(64 cols) @ BTf (2 ksteps), raw linear ----------------
__global__ __launch_bounds__(512, 4) void k_pr_gemm(
    const u16* __restrict__ featA, const u16* __restrict__ BTf,
    u16* __restrict__ out16, int M)
{
  const int tid = threadIdx.x;
  const int w = tid>>6, l = tid&63;
  const int lr = l&15, lq = l>>4;
  const int nrb = (M+15)>>4;
  bf16x8 B0[2], B1[2];
  #pragma unroll
  for (int ks=0; ks<2; ks++){
    B0[ks] = *(const bf16x8*)(BTf + (size_t)((ks*16 + w*2  )*512) + l*8);
    B1[ks] = *(const bf16x8*)(BTf + (size_t)((ks*16 + w*2+1)*512) + l*8);
  }
  const int c0 = w*32 + lr, c1 = w*32 + 16 + lr;
  for (int rb = blockIdx.x; rb < nrb; rb += gridDim.x){
    int r = rb*16 + lr; int rc = min(r, M-1);
    const u16* fr = featA + (size_t)rc*64 + lq*8;
    bf16x8 a0 = *(const bf16x8*)(fr);
    bf16x8 a1 = *(const bf16x8*)(fr + 32);
    f32x4 acc0 = (f32x4){0.f,0.f,0.f,0.f};
    f32x4 acc1 = (f32x4){0.f,0.f,0.f,0.f};
    acc0 = __builtin_amdgcn_mfma_f32_16x16x32_bf16(a0, B0[0], acc0, 0,0,0);
    acc0 = __builtin_amdgcn_mfma_f32_16x16x32_bf16(a1, B0[1], acc0, 0,0,0);
    acc1 = __builtin_amdgcn_mfma_f32_16x16x32_bf16(a0, B1[0], acc1, 0,0,0);
    acc1 = __builtin_amdgcn_mfma_f32_16x16x32_bf16(a1, B1[1], acc1, 0,0,0);
    #pragma unroll
    for (int reg=0; reg<4; reg++){
      int gm = rb*16 + lq*4 + reg;
      if (gm < M){
        out16[(size_t)gm*HD + c0] = f2b(acc0[reg]);
        out16[(size_t)gm*HD + c1] = f2b(acc1[reg]);
      }
    }
  }
}

// ---------------- fused node kernel: U[v] = Padd[v] + (alpha[v] + segsum(msg)) @ B ----------------
// dst-sorted edges: node v's msg rows are contiguous [start_d[v], start_d[v+1]).
// 512 thr = 8 waves; per group of 16 nodes: wave w seg-sums nodes 2w,2w+1 into LDS, then
// MFMA vs register-resident B (8 ksteps x 2 nj per wave).
// mode 0: out16 = U (raw, bf16).  mode 1: out32 = relu(val + bias) (output layer h).
__global__ __launch_bounds__(512, 4) void k_nodeU(
    const u16* __restrict__ msg, const u16* __restrict__ alpha16,
    const int* __restrict__ start_d, const u16* __restrict__ BTf,
    const u16* __restrict__ Padd, const float* __restrict__ bias,
    u16* __restrict__ out16, float* __restrict__ out32, int N, int mode)
{
  __shared__ u16 A_lds[16][AST];   // 8448 B
  const int tid = threadIdx.x;
  const int w = tid>>6, l = tid&63;
  const int lr = l&15, lq = l>>4;
  const int ngrp = (N+15)>>4;

  bf16x8 B0[8], B1[8];
  #pragma unroll
  for (int ks=0; ks<8; ks++){
    B0[ks] = *(const bf16x8*)(BTf + (size_t)((ks*16 + w*2  )*512) + l*8);
    B1[ks] = *(const bf16x8*)(BTf + (size_t)((ks*16 + w*2+1)*512) + l*8);
  }
  const int c0 = w*32 + lr, c1 = w*32 + 16 + lr;
  float b0 = 0.f, b1 = 0.f;
  if (mode == 1){ b0 = bias[c0]; b1 = bias[c1]; }

  for (int grp = blockIdx.x; grp < ngrp; grp += gridDim.x){
    const int vb = grp*16;
    // ---- phase A: streaming segment sums (contiguous msg rows), bf16 -> LDS
    #pragma unroll
    for (int h=0; h<2; h++){
      int v = vb + w*2 + h;
      float a[4] = {0.f,0.f,0.f,0.f};
      if (v < N){
        uint2 av = *(const uint2*)(alpha16 + (size_t)v*HD + l*4);
        a[0]=b2f((u16)av.x); a[1]=b2f((u16)(av.x>>16));
        a[2]=b2f((u16)av.y); a[3]=b2f((u16)(av.y>>16));
        int s = start_d[v], e2 = start_d[v+1];
        const u16* ml = msg + (size_t)s*HD + l*4;
        int cnt = e2 - s, j = 0;
        for (; j+2 <= cnt; j+=2){
          uint2 v0 = *(const uint2*)(ml);
          uint2 v1 = *(const uint2*)(ml + HD);
          ml += 2*HD;
          acc4(a, v0); acc4(a, v1);
        }
        for (; j < cnt; j++){
          uint2 v0 = *(const uint2*)(ml); ml += HD;
          acc4(a, v0);
        }
      }
      ushort4 o; o.x=f2b(a[0]); o.y=f2b(a[1]); o.z=f2b(a[2]); o.w=f2b(a[3]);
      *(ushort4*)&A_lds[w*2+h][l*4] = o;
    }
    __syncthreads();
    // ---- phase B: MFMA vs register B
    f32x4 acc0 = (f32x4){0.f,0.f,0.f,0.f};
    f32x4 acc1 = (f32x4){0.f,0.f,0.f,0.f};
    const u16* Ar = &A_lds[lr][0];
    #pragma unroll
    for (int ks=0; ks<8; ks++){
      bf16x8 af = *(const bf16x8*)(Ar + ks*32 + lq*8);
      acc0 = __builtin_amdgcn_mfma_f32_16x16x32_bf16(af, B0[ks], acc0, 0,0,0);
      acc1 = __builtin_amdgcn_mfma_f32_16x16x32_bf16(af, B1[ks], acc1, 0,0,0);
    }
    // ---- epilogue: col=lr-derived, row=lq*4+reg; add Padd row
    #pragma unroll
    for (int reg=0; reg<4; reg++){
      int gm = vb + lq*4 + reg;
      if (gm < N){
        float v0 = acc0[reg] + b2f(Padd[(size_t)gm*HD + c0]);
        float v1 = acc1[reg] + b2f(Padd[(size_t)gm*HD + c1]);
        if (mode == 1){
          v0 += b0; v1 += b1;
          out32[(size_t)gm*HD + c0] = v0 > 0.f ? v0 : 0.f;
          out32[(size_t)gm*HD + c1] = v1 > 0.f ? v1 : 0.f;
        } else {
          out16[(size_t)gm*HD + c0] = f2b(v0);
          out16[(size_t)gm*HD + c1] = f2b(v1);
        }
      }
    }
    __syncthreads();
  }
}

// ---------------- edge update: msg[e] = relu( U[src[e]] + xe[e] @ Wi[35:40] ) ----------------
// wave-per-edge; Wi edge-coeffs register-resident (20 floats/lane).
__global__ __launch_bounds__(256, 8) void k_edge_update(
    const u16* __restrict__ U, const float* __restrict__ xep,
    const int* __restrict__ esrc_p, const float* __restrict__ Wi,
    u16* __restrict__ msg, int E)
{
  const int l = threadIdx.x & 63;
  const int wid = (blockIdx.x*256 + threadIdx.x) >> 6;
  const int nw = gridDim.x*4;
  float wq[5][4];
  #pragma unroll
  for (int k=0;k<5;k++){
    float4 t = *(const float4*)(Wi + (size_t)(35+k)*HD + l*4);
    wq[k][0]=t.x; wq[k][1]=t.y; wq[k][2]=t.z; wq[k][3]=t.w;
  }
  for (int e = wid; e < E; e += nw){
    int s = esrc_p[e];
    const float* xp = xep + (size_t)e*5;
    float x0=xp[0], x1=xp[1], x2=xp[2], x3=xp[3], x4=xp[4];
    uint2 uv = *(const uint2*)(U + (size_t)s*HD + l*4);
    float v[4] = { b2f((u16)uv.x), b2f((u16)(uv.x>>16)),
                   b2f((u16)uv.y), b2f((u16)(uv.y>>16)) };
    #pragma unroll
    for (int j=0;j<4;j++){
      float q = x0*wq[0][j] + x1*wq[1][j] + x2*wq[2][j] + x3*wq[3][j] + x4*wq[4][j];
      float r = v[j] + q;
      v[j] = r > 0.f ? r : 0.f;
    }
    ushort4 o; o.x=f2b(v[0]); o.y=f2b(v[1]); o.z=f2b(v[2]); o.w=f2b(v[3]);
    *(ushort4*)(msg + (size_t)e*HD + l*4) = o;
  }
}

// ---------------- backtracking pair list (new labels; segments contiguous) ----------------
__global__ void k_pairs(const int* __restrict__ esrc_p, const int* __restrict__ edst_p,
                        const int* __restrict__ start_d,
                        int* __restrict__ npairs, int2* __restrict__ pairs, int E){
  int e = blockIdx.x*256 + threadIdx.x;
  if (e >= E) return;
  int u = esrc_p[e], v = edst_p[e];
  int s = start_d[u], t = start_d[u+1];
  for (int ep=s; ep<t; ep++){
    if (esrc_p[ep] == v){
      int pos = atomicAdd(npairs, 1);
      if (pos < CORR_CAP) pairs[pos] = (int2){e, ep};
    }
  }
}

// snapshot old msg rows of pair partners before msg overwrite
__global__ void k_snapshot(const u16* __restrict__ msg, const int2* __restrict__ pairs,
                           const int* __restrict__ npairs_p, u16* __restrict__ corrbuf){
  int np = *npairs_p; if (np > CORR_CAP) np = CORR_CAP;
  int wid = (blockIdx.x*256 + threadIdx.x) >> 6;
  int l = threadIdx.x & 63;
  int nw = gridDim.x * 4;
  for (int p = wid; p < np; p += nw){
    int ep = pairs[p].y;
    *(uint2*)(corrbuf + (size_t)p*HD + l*4) =
        *(const uint2*)(msg + (size_t)ep*HD + l*4);
  }
}

// exact recompute of backtracking-affected msg rows:
// msg[e] = relu( U[src] + xe@Wi_b - (sum of old partner msgs) @ Wh )
__global__ __launch_bounds__(256) void k_fixup(
    const u16* __restrict__ U, const float* __restrict__ xep,
    const int* __restrict__ esrc_p,
    const u16* __restrict__ corrbuf, const int2* __restrict__ pairs,
    const int* __restrict__ npairs_p, const float* __restrict__ Wi,
    const float* __restrict__ Wh, u16* __restrict__ msg){
  int np = *npairs_p; if (np > CORR_CAP) np = CORR_CAP;
  int t = threadIdx.x;
  __shared__ float cs[256];
  for (int p = blockIdx.x; p < np; p += gridDim.x){
    int e = pairs[p].x;
    bool first = true;
    for (int q=0;q<p;q++) if (pairs[q].x == e){ first = false; break; }
    if (!first) continue;                 // block-uniform
    float c = 0.f;
    for (int q=p;q<np;q++) if (pairs[q].x == e) c += b2f(corrbuf[(size_t)q*HD + t]);
    cs[t] = c; __syncthreads();
    float corr = 0.f;
    for (int k=0;k<HD;k++) corr += cs[k]*Wh[(size_t)k*HD + t];
    const float* xp = xep + (size_t)e*5;
    float qv = 0.f;
    for (int k=0;k<5;k++) qv += xp[k]*Wi[(size_t)(35+k)*HD + t];
    int u = esrc_p[e];
    float val = b2f(U[(size_t)u*HD + t]) + qv - corr;
    msg[(size_t)e*HD + t] = f2b(val > 0.f ? val : 0.f);
    __syncthreads();
  }
}

// ---------------- graph mean (graph_ids sorted), fp32 in/out ----------------
__global__ void k_graph_mean(const float* __restrict__ h, const int* __restrict__ gid,
                             int N, int G, float* __restrict__ out){
  int g = (int)(((long long)blockIdx.x*blockDim.x + threadIdx.x)>>6);
  int l = threadIdx.x & 63;
  if (g >= G) return;
  int lo=0, hi=N;
  while (lo<hi){ int mid=(lo+hi)>>1; if (gid[mid] < g) lo=mid+1; else hi=mid; }
  int b = lo;
  hi = N;
  while (lo<hi){ int mid=(lo+hi)>>1; if (gid[mid] < g+1) lo=mid+1; else hi=mid; }
  int e2 = lo;
  float a0=0.f,a1=0.f,a2=0.f,a3=0.f;
  for (int v=b; v<e2; v++){
    float4 hv = *(const float4*)(h + (size_t)v*HD + l*4);
    a0 += hv.x; a1 += hv.y; a2 += hv.z; a3 += hv.w;
  }
  int cnt = e2 - b; if (cnt < 1) cnt = 1;
  float inv = 1.0f/(float)cnt;
  float4 o; o.x=a0*inv; o.y=a1*inv; o.z=a2*inv; o.w=a3*inv;
  *(float4*)(out + (size_t)g*HD + l*4) = o;
}

extern "C" void kernel_launch(void* const* d_in, const int* in_sizes, int n_in,
                              void* d_out, int out_size, void* d_ws, size_t ws_size,
                              hipStream_t stream){
  const float* x_nodes = (const float*)d_in[0];
  const float* x_edges = (const float*)d_in[1];
  const float* tree_m  = (const float*)d_in[2];
  const float* W_i     = (const float*)d_in[3];
  const float* W_h     = (const float*)d_in[4];
  const float* W_o     = (const float*)d_in[5];
  const float* b_o     = (const float*)d_in[6];
  const int* edge_src = (const int*)d_in[7];
  const int* edge_dst = (const int*)d_in[8];
  const int* tgt      = (const int*)d_in[11];
  const int* teid     = (const int*)d_in[12];
  const int* gid      = (const int*)d_in[13];

  const int N = in_sizes[0]/35;
  const int E = in_sizes[1]/5;
  const int K = in_sizes[11];
  const int G = out_size/HD;

  // ---- workspace layout (~221 MB footprint) ----
  char* wsb = (char*)d_ws;
  auto align256 = [](size_t x){ return (x + 255) & ~(size_t)255; };
  size_t oMsg    = 0;
  size_t oAlpha  = oMsg    + align256((size_t)E*HD*2);        // 102.4 MB
  size_t oU      = oAlpha  + align256((size_t)N*HD*2);        // 25.6 MB
  size_t oP      = oU      + align256((size_t)N*HD*2);        // 25.6 MB (U+P = hbuf overlay)
  size_t oR      = oP      + align256((size_t)N*HD*2);        // 25.6 MB
  size_t oXnf    = oR      + align256((size_t)N*HD*2);        // 6.4 MB
  size_t oXep    = oXnf    + align256((size_t)N*64*2);        // 4.0 MB
  size_t oBTP    = oXep    + align256((size_t)E*5*4);         // 32 KB (2 ks)
  size_t oBTWh   = oBTP    + align256((size_t)2*16*512*2);    // 128 KB (8 ks)
  size_t oBTRa   = oBTWh   + align256((size_t)8*16*512*2);    // 32 KB
  size_t oBTWob  = oBTRa   + align256((size_t)2*16*512*2);    // 128 KB
  size_t oDegD   = oBTWob  + align256((size_t)8*16*512*2);    // N+1 ints ([N] = npairs)
  size_t oStartD = oDegD   + align256((size_t)(N+1)*4);
  size_t oCurD   = oStartD + align256((size_t)(N+1)*4);
  size_t oPerm   = oCurD   + align256((size_t)N*4);
  size_t oEsrcP  = oPerm   + align256((size_t)E*4);
  size_t oEdstP  = oEsrcP  + align256((size_t)E*4);
  size_t oDegT   = oEdstP  + align256((size_t)E*4);
  size_t oStartT = oDegT   + align256((size_t)N*4);
  size_t oCurT   = oStartT + align256((size_t)(N+1)*4);
  size_t oBukT   = oCurT   + align256((size_t)N*4);
  size_t oBsum   = oBukT   + align256((size_t)K*4);
  size_t oPairs  = oBsum   + align256((size_t)1024*4);
  size_t oCorrB  = oPairs  + align256((size_t)CORR_CAP*8);    // 1 MB

  u16*   msg     = (u16*)(wsb + oMsg);
  u16*   alpha16 = (u16*)(wsb + oAlpha);
  u16*   U       = (u16*)(wsb + oU);
  u16*   P       = (u16*)(wsb + oP);
  u16*   R       = (u16*)(wsb + oR);
  u16*   xnf     = (u16*)(wsb + oXnf);
  float* xep     = (float*)(wsb + oXep);
  u16*   BT_P    = (u16*)(wsb + oBTP);
  u16*   BT_Wh   = (u16*)(wsb + oBTWh);
  u16*   BT_Ra   = (u16*)(wsb + oBTRa);
  u16*   BT_Wob  = (u16*)(wsb + oBTWob);
  int*   deg_d   = (int*)(wsb + oDegD);
  int*   npairs  = deg_d + N;                 // zeroed together with deg_d
  int*   start_d = (int*)(wsb + oStartD);
  int*   cur_d   = (int*)(wsb + oCurD);
  int*   perm    = (int*)(wsb + oPerm);
  int*   esrc_p  = (int*)(wsb + oEsrcP);
  int*   edst_p  = (int*)(wsb + oEdstP);
  int*   deg_t   = (int*)(wsb + oDegT);
  int*   start_t = (int*)(wsb + oStartT);
  int*   cur_t   = (int*)(wsb + oCurT);
  int*   buk_t   = (int*)(wsb + oBukT);
  int*   bsum    = (int*)(wsb + oBsum);
  int2*  pairs   = (int2*)(wsb + oPairs);
  u16*   corrbuf = (u16*)(wsb + oCorrB);
  // hbuf (N*HD fp32 = 51.2 MB) overlays U+P: both dead before the output-layer k_nodeU
  float* hbuf    = (float*)(wsb + oU);

  const int egrid256 = (E+255)/256;
  const int kgrid256 = (K+255)/256;
  const int ngrid256 = (N+255)/256;
  const int nbN      = (N+255)/256;

  // ---- B tables: P-part of Wi (k<35), Wh, R-part of Wo (k<35), node-part of Wo (rows 35..290)
  k_prep_frag<<<64,  256, 0, stream>>>(W_i, 0, 35, 2, BT_P);
  k_prep_frag<<<256, 256, 0, stream>>>(W_h, 0, 256, 8, BT_Wh);
  k_prep_frag<<<64,  256, 0, stream>>>(W_o, 0, 35, 2, BT_Ra);
  k_prep_frag<<<256, 256, 0, stream>>>(W_o, 35, 256, 8, BT_Wob);

  // ---- dst-CSR -> edge permutation (new label = dst-sorted rank)
  k_zero_int<<<(N+1+255)/256, 256, 0, stream>>>(deg_d, N+1);
  k_hist<<<egrid256, 256, 0, stream>>>(edge_dst, deg_d, E);
  k_scan_p1<<<nbN, 256, 0, stream>>>(deg_d, N, bsum);
  k_scan_p2<<<1, 1024, 0, stream>>>(bsum, nbN, start_d + N);   // start_d[N] = E
  k_scan_p3<<<nbN, 256, 0, stream>>>(deg_d, bsum, N, start_d, cur_d);
  k_fill<<<egrid256, 256, 0, stream>>>(edge_dst, (const int*)0, cur_d, perm, E);
  k_permarr<<<egrid256, 256, 0, stream>>>(perm, edge_src, edge_dst, esrc_p, edst_p, E);
  k_xep<<<egrid256, 256, 0, stream>>>(x_edges, perm, xep, E);
  k_xnf<<<((size_t)N*64+255)/256, 256, 0, stream>>>(x_nodes, xnf, N);

  // ---- tgt-CSR + alpha gather
  k_zero_int<<<ngrid256, 256, 0, stream>>>(deg_t, N);
  k_hist<<<kgrid256, 256, 0, stream>>>(tgt, deg_t, K);
  k_scan_p1<<<nbN, 256, 0, stream>>>(deg_t, N, bsum);
  k_scan_p2<<<1, 1024, 0, stream>>>(bsum, nbN, start_t + N);   // start_t[N] = K
  k_scan_p3<<<nbN, 256, 0, stream>>>(deg_t, bsum, N, start_t, cur_t);
  k_fill<<<kgrid256, 256, 0, stream>>>(tgt, teid, cur_t, buk_t, K);
  k_alpha_gather<<<(N+3)/4, 256, 0, stream>>>(tree_m, start_t, buk_t, alpha16, N);

  k_pairs<<<egrid256, 256, 0, stream>>>(esrc_p, edst_p, start_d, npairs, pairs, E);

  // ---- P = xn@Wi_a, R = xn@Wo_a (raw linear, bf16)
  k_pr_gemm<<<512, 512, 0, stream>>>(xnf, BT_P, P, N);
  k_pr_gemm<<<512, 512, 0, stream>>>(xnf, BT_Ra, R, N);

  // ---- iter0: msg = relu(P[src] + xe@Wi_b)
  k_edge_update<<<2048, 256, 0, stream>>>(P, xep, esrc_p, W_i, msg, E);

  // ---- BP iters: U = P + (alpha + segsum(msg))@Wh; snapshot; edge update; fixup
  for (int it=0; it<3; ++it){
    k_nodeU<<<512, 512, 0, stream>>>(msg, alpha16, start_d, BT_Wh, P,
                                     (const float*)0, U, (float*)0, N, 0);
    k_snapshot<<<32, 256, 0, stream>>>(msg, pairs, npairs, corrbuf);
    k_edge_update<<<2048, 256, 0, stream>>>(U, xep, esrc_p, W_i, msg, E);
    k_fixup<<<64, 256, 0, stream>>>(U, xep, esrc_p, corrbuf, pairs, npairs,
                                    W_i, W_h, msg);
  }

  // ---- output layer: h = relu(R + (alpha + segsum(msg))@Wo_b + b) -> hbuf (fp32)
  k_nodeU<<<512, 512, 0, stream>>>(msg, alpha16, start_d, BT_Wob, R,
                                   b_o, (u16*)0, hbuf, N, 1);
  k_graph_mean<<<(G+3)/4, 256, 0, stream>>>(hbuf, gid, N, G, (float*)d_out);
}